// Round 12
// baseline (483.948 us; speedup 1.0000x reference)
//
#include <hip/hip_runtime.h>
#include <hip/hip_bf16.h>
#include <stdint.h>

// JinaEmbeddingsV3SelfOutput, algebraically folded:
//   h2 = hs @ Weff_t^T + beff_t,   Weff_t = W@W + 0.25*B_t@(A_t@W)  [per task]
//   beff_t = W@b + b + 0.25*B_t@(A_t@b)
//   out = LN(h2 + input)
// R12: cvt rebuilt with FORCED memory-level parallelism: 8 jobs/thread, all
//      16 global_load_dwordx4 issued via `asm volatile` (cannot be reordered
//      or sunk — unlike sched_barrier, which a later machine pass ignored in
//      R8) before a single vmcnt(0). In-flight bytes/wave: 64 B (all prior
//      variants, ~1.6 TB/s) -> 16 KB. cvt blocks 16352 -> 2048, still
//      co-scheduled into K1/K2/K3. gemm_main + ln4 + prep compute byte-
//      identical to R11.
#define D_HID 1024
#define M_TOT 32768
#define LN_EPS 1e-5f

typedef __bf16 bf16x8 __attribute__((ext_vector_type(8)));
typedef float f32x4 __attribute__((ext_vector_type(4)));
typedef unsigned short u16;
typedef u16 u16x8 __attribute__((ext_vector_type(8)));
typedef u16 u16x4v __attribute__((ext_vector_type(4)));

__device__ __forceinline__ float bf2f(u16 x) {
  union { unsigned int u; float f; } c; c.u = ((unsigned int)x) << 16; return c.f;
}
__device__ __forceinline__ u16 f2bf(float f) {
  union { __bf16 h; u16 u; } c; c.h = (__bf16)f; return c.u;  // RNE
}
// Async global->LDS, 16B/lane. LDS dest is wave-uniform base + lane*16.
__device__ __forceinline__ void gld16(const u16* g, u16* lds_wave_base) {
  __builtin_amdgcn_global_load_lds(
      (__attribute__((address_space(1))) unsigned int*)g,
      (__attribute__((address_space(3))) unsigned int*)lds_wave_base, 16, 0, 0);
}

// ---- deep-MLP cvt: 8 jobs/thread, 16 asm-issued loads -> one vmcnt(0) ----
// job j covers hs[j*8 .. j*8+8). Slot-s job = joff + gtid + s*T (coalesced:
// consecutive lanes -> consecutive jobs for every slot).
#define CVT1_BLKS 680
#define CVT2_BLKS 684
#define CVT3_BLKS 684
#define CVT1_T (CVT1_BLKS * 256)
#define CVT2_T (CVT2_BLKS * 256)
#define CVT3_T (CVT3_BLKS * 256)
#define CVT2_JOFF ((size_t)CVT1_BLKS * 2048)
#define CVT3_JOFF ((size_t)(CVT1_BLKS + CVT2_BLKS) * 2048)

__device__ __forceinline__ void cvt_deep(const float* __restrict__ hs,
                                         u16* __restrict__ hs_bf,
                                         size_t joff, int gtid, int T) {
  f32x4 v[16];
#pragma unroll
  for (int s = 0; s < 8; ++s) {
    const size_t j = joff + (size_t)gtid + (size_t)s * T;
    uint64_t a = (uint64_t)(hs + j * 8);
    asm volatile("global_load_dwordx4 %0, %1, off" : "=v"(v[2 * s]) : "v"(a));
    asm volatile("global_load_dwordx4 %0, %1, off"
                 : "=v"(v[2 * s + 1]) : "v"(a + 16));
  }
  asm volatile("s_waitcnt vmcnt(0)" ::: "memory");
  __builtin_amdgcn_sched_barrier(0);
#pragma unroll
  for (int s = 0; s < 8; ++s) {
    const size_t j = joff + (size_t)gtid + (size_t)s * T;
    u16x8 o;
    o[0] = f2bf(v[2 * s][0]);     o[1] = f2bf(v[2 * s][1]);
    o[2] = f2bf(v[2 * s][2]);     o[3] = f2bf(v[2 * s][3]);
    o[4] = f2bf(v[2 * s + 1][0]); o[5] = f2bf(v[2 * s + 1][1]);
    o[6] = f2bf(v[2 * s + 1][2]); o[7] = f2bf(v[2 * s + 1][3]);
    *(u16x8*)(hs_bf + j * 8) = o;
  }
}

// ---- K1: W split+transpose (0..1023), lA zero-pad split (1024..1031),
//          deep cvt slice (1032..1711) ----
__global__ __launch_bounds__(256) void k1_prep(
    const float* __restrict__ hs, u16* __restrict__ hs_bf,
    const float* __restrict__ W, u16* __restrict__ hi, u16* __restrict__ lo,
    u16* __restrict__ hiT, u16* __restrict__ loT,
    const float* __restrict__ lA, u16* __restrict__ lAh, u16* __restrict__ lAl) {
  __shared__ float tile[32][33];
  const int bid = blockIdx.x, tid = threadIdx.x;
  if (bid >= 1032) {
    cvt_deep(hs, hs_bf, 0, (bid - 1032) * 256 + tid, CVT1_T);
    return;
  }
  if (bid >= 1024) {                  // lA pad+split: 128x1024, rows >=20 zero
    const int b = bid - 1024;
    for (int i = tid; i < 16 * 1024; i += 256) {
      const int r = b * 16 + (i >> 10), c = i & 1023;
      const float v = (r < 20) ? lA[(size_t)r * 1024 + c] : 0.f;
      const u16 h = f2bf(v);
      lAh[(size_t)r * 1024 + c] = h;
      lAl[(size_t)r * 1024 + c] = f2bf(v - bf2f(h));
    }
    return;
  }
  const int bj = bid & 31, bi = bid >> 5;
  const int tx = tid & 31, ty = tid >> 5;
#pragma unroll
  for (int r0 = 0; r0 < 32; r0 += 8) {
    const int r = r0 + ty;
    const size_t o = (size_t)(bi * 32 + r) * D_HID + bj * 32 + tx;
    const float v = W[o];
    tile[r][tx] = v;
    const u16 h = f2bf(v);
    hi[o] = h; lo[o] = f2bf(v - bf2f(h));
  }
  __syncthreads();
#pragma unroll
  for (int r0 = 0; r0 < 32; r0 += 8) {
    const int r = r0 + ty;
    const float v = tile[tx][r];
    const size_t o = (size_t)(bj * 32 + r) * D_HID + bi * 32 + tx;
    const u16 h = f2bf(v);
    hiT[o] = h; loT[o] = f2bf(v - bf2f(h));
  }
}

// ---- K2: [W; lApad] @ W split-bf16 MFMA 64x64 (0..271) + deep cvt (272..955) ----
__global__ __launch_bounds__(256) void k2_s2(
    const u16* __restrict__ Ah, const u16* __restrict__ Al,
    const u16* __restrict__ Bh, const u16* __restrict__ Bl,
    const u16* __restrict__ lAh, const u16* __restrict__ lAl,
    const float* __restrict__ hs, u16* __restrict__ hs_bf,
    float* __restrict__ C, float* __restrict__ A2) {
  __shared__ __align__(16) u16 smem[4][64 * 32];   // Ah,Al,Bh,Bl tiles
  const int bid = blockIdx.x, tid = threadIdx.x;
  if (bid >= 272) {
    cvt_deep(hs, hs_bf, CVT2_JOFF, (bid - 272) * 256 + tid, CVT2_T);
    return;
  }
  const int wave = tid >> 6, lane = tid & 63;
  const int by = bid >> 4, bx = bid & 15;
  const bool isA2 = (by == 16);
  const u16* Asel_h = isA2 ? lAh : Ah;
  const u16* Asel_l = isA2 ? lAl : Al;
  const int arow0 = isA2 ? 0 : by * 64;
  const u16* gsel = (wave == 0) ? Asel_h : (wave == 1) ? Asel_l
                  : (wave == 2) ? Bh : Bl;
  const int rb = (wave < 2) ? arow0 : bx * 64;
  const u16* gp = gsel + (size_t)(rb + (lane >> 2)) * D_HID + (lane & 3) * 8;
  u16* sb = &smem[wave][0];

  const int l15 = lane & 15, quad = lane >> 4;
  const int wm = wave >> 1, wn = wave & 1;
  const int fA = (wm * 32 + l15) * 32 + quad * 8;
  const int fB = (wn * 32 + l15) * 32 + quad * 8;
  f32x4 acc[2][2];
#pragma unroll
  for (int m = 0; m < 2; ++m)
#pragma unroll
    for (int n = 0; n < 2; ++n) acc[m][n] = (f32x4){0.f, 0.f, 0.f, 0.f};

  for (int k0 = 0; k0 < D_HID; k0 += 32) {
    __syncthreads();
#pragma unroll
    for (int q = 0; q < 4; ++q)
      gld16(gp + (size_t)q * 16 * D_HID, sb + q * 512);
    gp += 32;
    __syncthreads();
    bf16x8 ahf[2], alf[2], bhf[2], blf[2];
#pragma unroll
    for (int m = 0; m < 2; ++m) {
      ahf[m] = *(const bf16x8*)(&smem[0][fA + m * 512]);
      alf[m] = *(const bf16x8*)(&smem[1][fA + m * 512]);
    }
#pragma unroll
    for (int n = 0; n < 2; ++n) {
      bhf[n] = *(const bf16x8*)(&smem[2][fB + n * 512]);
      blf[n] = *(const bf16x8*)(&smem[3][fB + n * 512]);
    }
#pragma unroll
    for (int m = 0; m < 2; ++m)
#pragma unroll
      for (int n = 0; n < 2; ++n) {
        acc[m][n] = __builtin_amdgcn_mfma_f32_16x16x32_bf16(ahf[m], bhf[n], acc[m][n], 0, 0, 0);
        acc[m][n] = __builtin_amdgcn_mfma_f32_16x16x32_bf16(alf[m], bhf[n], acc[m][n], 0, 0, 0);
        acc[m][n] = __builtin_amdgcn_mfma_f32_16x16x32_bf16(ahf[m], blf[n], acc[m][n], 0, 0, 0);
      }
  }
  const int nn0 = bx * 64 + wn * 32;
#pragma unroll
  for (int m = 0; m < 2; ++m)
#pragma unroll
    for (int n = 0; n < 2; ++n) {
      const int nn = nn0 + n * 16 + l15;
#pragma unroll
      for (int r = 0; r < 4; ++r) {
        const int lr = wm * 32 + m * 16 + quad * 4 + r;
        if (!isA2) {
          C[(size_t)(by * 64 + lr) * D_HID + nn] = acc[m][n][r];
        } else if (lr < 20) {
          A2[(size_t)lr * D_HID + nn] = acc[m][n][r];
        }
      }
    }
}

// ---- K3: weff+beff (0..5119) + deep cvt (5120..5803) ----
__global__ __launch_bounds__(256) void k3_weff(
    const float* __restrict__ Wc, const float* __restrict__ A2,
    const float* __restrict__ lB, const float* __restrict__ lA,
    const float* __restrict__ W, const float* __restrict__ bvec,
    const float* __restrict__ hs, u16* __restrict__ hs_bf,
    u16* __restrict__ Weff, float* __restrict__ beff) {
  const int bid = blockIdx.x, tid = threadIdx.x;
  if (bid >= 5120) {
    cvt_deep(hs, hs_bf, CVT3_JOFF, (bid - 5120) * 256 + tid, CVT3_T);
    return;
  }
  const int n = bid & 1023, t = bid >> 10;
  const int wave = tid >> 6, lane = tid & 63;
  float br[4];
#pragma unroll
  for (int r = 0; r < 4; ++r) br[r] = lB[(size_t)t * 4096 + n * 4 + r];
  float4 v = *(const float4*)(Wc + (size_t)n * D_HID + tid * 4);
#pragma unroll
  for (int r = 0; r < 4; ++r) {
    const float4 a2 = *(const float4*)(A2 + (size_t)(t * 4 + r) * D_HID + tid * 4);
    const float s = 0.25f * br[r];
    v.x += s * a2.x; v.y += s * a2.y; v.z += s * a2.z; v.w += s * a2.w;
  }
  u16x4v o; o[0] = f2bf(v.x); o[1] = f2bf(v.y); o[2] = f2bf(v.z); o[3] = f2bf(v.w);
  *(u16x4v*)(Weff + (size_t)t * 1048576 + (size_t)n * D_HID + tid * 4) = o;
  const float4 bb = *(const float4*)(bvec + tid * 4);
  float p[5];
  {
    const float4 wr = *(const float4*)(W + (size_t)n * D_HID + tid * 4);
    p[0] = wr.x * bb.x + wr.y * bb.y + wr.z * bb.z + wr.w * bb.w;
  }
#pragma unroll
  for (int r = 0; r < 4; ++r) {
    const float4 ar = *(const float4*)(lA + (size_t)(t * 4 + r) * D_HID + tid * 4);
    p[1 + r] = ar.x * bb.x + ar.y * bb.y + ar.z * bb.z + ar.w * bb.w;
  }
#pragma unroll
  for (int m = 1; m < 64; m <<= 1)
#pragma unroll
    for (int jj = 0; jj < 5; ++jj) p[jj] += __shfl_xor(p[jj], m);
  __shared__ float red[4][5];
  if (lane == 0)
#pragma unroll
    for (int jj = 0; jj < 5; ++jj) red[wave][jj] = p[jj];
  __syncthreads();
  if (tid == 0) {
    float P = 0.f, Cr[4] = {0.f, 0.f, 0.f, 0.f};
#pragma unroll
    for (int w = 0; w < 4; ++w) {
      P += red[w][0];
#pragma unroll
      for (int r = 0; r < 4; ++r) Cr[r] += red[w][1 + r];
    }
    const float e = br[0]*Cr[0] + br[1]*Cr[1] + br[2]*Cr[2] + br[3]*Cr[3];
    beff[t * D_HID + n] = P + bvec[n] + 0.25f * e;
  }
}

// ---- main GEMM: h2 = hs_bf @ Weff[task]^T + beff (store-only epilogue).
//      256x256, BK=64, 8 waves, 128 KB dbuf, 8-phase counted-vmcnt schedule
//      with XOR octet swizzle (R10/R11 verbatim — 92 us, MfmaUtil 31). ----
__global__ __launch_bounds__(512, 1) void gemm_main(
    const u16* __restrict__ Ag, const u16* __restrict__ Wf,
    const float* __restrict__ beff, const int* __restrict__ mask,
    float* __restrict__ out) {
  __shared__ __align__(16) u16 sAf[2 * 16384];
  __shared__ __align__(16) u16 sBf[2 * 16384];
  const int tid = threadIdx.x, wave = tid >> 6, lane = tid & 63;
  const int L = blockIdx.x;                 // 512 blocks
  const int xcd = L & 7, j = L >> 3;
  const int bx = j & 3;                     // N-tile 0..3
  const int by = xcd * 16 + (j >> 2);       // M-tile 0..127; XCD-clustered
  const int task = mask[by >> 3];           // 256-row tile never crosses batch
  const u16* Bg = Wf + (size_t)task * (D_HID * D_HID);

  const int acol = ((lane & 7) ^ (lane >> 3)) * 8;
  const int aBase = (by * 256 + wave * 8 + (lane >> 3)) * D_HID + acol;
  const int bBase = (bx * 256 + wave * 8 + (lane >> 3)) * D_HID + acol;

  auto stageA = [&](int ktar, int half) {
#pragma unroll
    for (int q = 0; q < 2; ++q)
      gld16(Ag + (aBase + ktar * 64 + half * 131072 + q * 65536),
            sAf + ((ktar & 1) * 16384 + half * 8192 + q * 4096 + wave * 512));
  };
  auto stageB = [&](int ktar, int half) {
#pragma unroll
    for (int q = 0; q < 2; ++q)
      gld16(Bg + (bBase + ktar * 64 + half * 131072 + q * 65536),
            sBf + ((ktar & 1) * 16384 + half * 8192 + q * 4096 + wave * 512));
  };

  const int wm = wave >> 2, wn = wave & 3;
  const int l15 = lane & 15, quad = lane >> 4, l7 = lane & 7;
  const int vA0 = (wm * 128 + l15) * 64 + ((quad ^ l7) * 8);
  const int vB0 = (wn * 64 + l15) * 64 + ((quad ^ l7) * 8);

  f32x4 acc[8][4];
#pragma unroll
  for (int i = 0; i < 8; ++i)
#pragma unroll
    for (int jn = 0; jn < 4; ++jn) acc[i][jn] = (f32x4){0.f, 0.f, 0.f, 0.f};

  stageB(0, 0); stageB(0, 1); stageA(0, 0); stageA(0, 1);
  stageB(1, 0); stageA(1, 0);
  asm volatile("s_waitcnt vmcnt(4)" ::: "memory");
  __builtin_amdgcn_s_barrier();
  __builtin_amdgcn_sched_barrier(0);

  bf16x8 a[4][2], b[4][2];
#pragma unroll 1
  for (int k2 = 0; k2 < 8; ++k2) {
#pragma unroll
    for (int par = 0; par < 2; ++par) {
      const int kt = k2 * 2 + par;
      const u16* pA = sAf + par * 16384;
      const u16* pB = sBf + par * 16384;
      const bool st01 = (par == 0) || (k2 < 7);  // kt < 15
      const bool st23 = (k2 < 7);                // kt < 14

      // -------- phase 0: (qm0, qn0) --------
#pragma unroll
      for (int m4 = 0; m4 < 4; ++m4) {
        a[m4][0] = *(const bf16x8*)(pA + (vA0 + m4 * 1024));
        a[m4][1] = *(const bf16x8*)(pA + ((vA0 ^ 32) + m4 * 1024));
      }
#pragma unroll
      for (int n2 = 0; n2 < 2; ++n2) {
        b[n2][0] = *(const bf16x8*)(pB + (vB0 + n2 * 1024));
        b[n2][1] = *(const bf16x8*)(pB + ((vB0 ^ 32) + n2 * 1024));
      }
      if (st01) stageB(kt + 1, 1);
      __builtin_amdgcn_s_barrier();
      asm volatile("s_waitcnt lgkmcnt(0)" ::: "memory");
      __builtin_amdgcn_sched_barrier(0);
      __builtin_amdgcn_s_setprio(1);
#pragma unroll
      for (int m4 = 0; m4 < 4; ++m4)
#pragma unroll
        for (int n2 = 0; n2 < 2; ++n2)
#pragma unroll
          for (int kk = 0; kk < 2; ++kk)
            acc[m4][n2] = __builtin_amdgcn_mfma_f32_16x16x32_bf16(
                a[m4][kk], b[n2][kk], acc[m4][n2], 0, 0, 0);
      __builtin_amdgcn_s_setprio(0);
      __builtin_amdgcn_s_barrier();
      __builtin_amdgcn_sched_barrier(0);

      // -------- phase 1: (qm0, qn1) --------
#pragma unroll
      for (int n2 = 0; n2 < 2; ++n2) {
        b[2 + n2][0] = *(const bf16x8*)(pB + (vB0 + (2 + n2) * 1024));
        b[2 + n2][1] = *(const bf16x8*)(pB + ((vB0 ^ 32) + (2 + n2) * 1024));
      }
      if (st01) stageA(kt + 1, 1);
      __builtin_amdgcn_s_barrier();
      asm volatile("s_waitcnt lgkmcnt(0)" ::: "memory");
      __builtin_amdgcn_sched_barrier(0);
      __builtin_amdgcn_s_setprio(1);
#pragma unroll
      for (int m4 = 0; m4 < 4; ++m4)
#pragma unroll
        for (int n2 = 0; n2 < 2; ++n2)
#pragma unroll
          for (int kk = 0; kk < 2; ++kk)
            acc[m4][2 + n2] = __builtin_amdgcn_mfma_f32_16x16x32_bf16(
                a[m4][kk], b[2 + n2][kk], acc[m4][2 + n2], 0, 0, 0);
      __builtin_amdgcn_s_setprio(0);
      __builtin_amdgcn_s_barrier();
      __builtin_amdgcn_sched_barrier(0);

      // -------- phase 2: (qm1, qn0) --------
#pragma unroll
      for (int m4 = 0; m4 < 4; ++m4) {
        a[m4][0] = *(const bf16x8*)(pA + (vA0 + (4 + m4) * 1024));
        a[m4][1] = *(const bf16x8*)(pA + ((vA0 ^ 32) + (4 + m4) * 1024));
      }
      if (st23) stageB(kt + 2, 0);
      __builtin_amdgcn_s_barrier();
      asm volatile("s_waitcnt lgkmcnt(0)" ::: "memory");
      __builtin_amdgcn_sched_barrier(0);
      __builtin_amdgcn_s_setprio(1);
#pragma unroll
      for (int m4 = 0; m4 < 4; ++m4)
#pragma unroll
        for (int n2 = 0; n2 < 2; ++n2)
#pragma unroll
          for (int kk = 0; kk < 2; ++kk)
            acc[4 + m4][n2] = __builtin_amdgcn_mfma_f32_16x16x32_bf16(
                a[m4][kk], b[n2][kk], acc[4 + m4][n2], 0, 0, 0);
      __builtin_amdgcn_s_setprio(0);
      __builtin_amdgcn_s_barrier();
      __builtin_amdgcn_sched_barrier(0);

      // -------- phase 3: (qm1, qn1) --------
      if (st23) stageA(kt + 2, 0);
      if (par == 0) {
        if (k2 < 7) { asm volatile("s_waitcnt vmcnt(4)" ::: "memory"); }
        else        { asm volatile("s_waitcnt vmcnt(0)" ::: "memory"); }
      } else {
        if (k2 < 7) { asm volatile("s_waitcnt vmcnt(4)" ::: "memory"); }
      }
      __builtin_amdgcn_s_barrier();
      asm volatile("s_waitcnt lgkmcnt(0)" ::: "memory");
      __builtin_amdgcn_sched_barrier(0);
      __builtin_amdgcn_s_setprio(1);
#pragma unroll
      for (int m4 = 0; m4 < 4; ++m4)
#pragma unroll
        for (int n2 = 0; n2 < 2; ++n2)
#pragma unroll
          for (int kk = 0; kk < 2; ++kk)
            acc[4 + m4][2 + n2] = __builtin_amdgcn_mfma_f32_16x16x32_bf16(
                a[m4][kk], b[2 + n2][kk], acc[4 + m4][2 + n2], 0, 0, 0);
      __builtin_amdgcn_s_setprio(0);
      __builtin_amdgcn_s_barrier();
      __builtin_amdgcn_sched_barrier(0);
    }
  }

  // store-only epilogue: h2 = acc + beff. C/D: col=lane&15, row=quad*4+r.
  const float* bb = beff + task * D_HID;
  const size_t mBase = (size_t)by * 256 + wm * 128;
  const int nb0 = bx * 256 + wn * 64;
#pragma unroll
  for (int mf = 0; mf < 8; ++mf)
#pragma unroll
    for (int nf = 0; nf < 4; ++nf) {
      const int n = nb0 + nf * 16 + l15;
      const float bval = bb[n];
#pragma unroll
      for (int r = 0; r < 4; ++r) {
        const size_t m = mBase + mf * 16 + quad * 4 + r;
        out[m * D_HID + n] = acc[mf][nf][r] + bval;
      }
    }
}

// ---- ln4: out = LN(h2 + resid); one wave per row; coalesced chunks ----
__global__ __launch_bounds__(256) void ln4(float* __restrict__ io,
                                           const float* __restrict__ resid,
                                           const float* __restrict__ gamma,
                                           const float* __restrict__ beta) {
  const int row = blockIdx.x * 4 + (threadIdx.x >> 6);
  const int lane = threadIdx.x & 63;
  float* p = io + (size_t)row * D_HID + lane * 4;
  const float* rp = resid + (size_t)row * D_HID + lane * 4;
  float4 v[4];
#pragma unroll
  for (int k = 0; k < 4; ++k) {
    const float4 h = *(const float4*)(p + k * 256);
    const float4 r = *(const float4*)(rp + k * 256);
    v[k].x = h.x + r.x; v[k].y = h.y + r.y;
    v[k].z = h.z + r.z; v[k].w = h.w + r.w;
  }
  float s = 0.f, q = 0.f;
#pragma unroll
  for (int k = 0; k < 4; ++k) {
    s += v[k].x + v[k].y + v[k].z + v[k].w;
    q += v[k].x * v[k].x + v[k].y * v[k].y + v[k].z * v[k].z + v[k].w * v[k].w;
  }
#pragma unroll
  for (int m = 1; m < 64; m <<= 1) { s += __shfl_xor(s, m); q += __shfl_xor(q, m); }
  const float mu  = s * (1.f / (float)D_HID);
  const float var = q * (1.f / (float)D_HID) - mu * mu;
  const float inv = rsqrtf(var + LN_EPS);
#pragma unroll
  for (int k = 0; k < 4; ++k) {
    const float4 g  = *(const float4*)(gamma + lane * 4 + k * 256);
    const float4 bb = *(const float4*)(beta + lane * 4 + k * 256);
    float4 o;
    o.x = (v[k].x - mu) * inv * g.x + bb.x;
    o.y = (v[k].y - mu) * inv * g.y + bb.y;
    o.z = (v[k].z - mu) * inv * g.z + bb.z;
    o.w = (v[k].w - mu) * inv * g.w + bb.w;
    *(float4*)(p + k * 256) = o;
  }
}

extern "C" void kernel_launch(void* const* d_in, const int* in_sizes, int n_in,
                              void* d_out, int out_size, void* d_ws, size_t ws_size,
                              hipStream_t stream) {
  const float* hs    = (const float*)d_in[0];  // [16,2048,1024] fp32
  const float* inp   = (const float*)d_in[1];  // [16,2048,1024] fp32
  const float* W     = (const float*)d_in[2];  // [1024,1024] fp32
  const float* b     = (const float*)d_in[3];  // [1024]
  const float* lA    = (const float*)d_in[4];  // [5,4,1024]
  const float* lB    = (const float*)d_in[5];  // [5,1024,4]
  const float* gamma = (const float*)d_in[6];
  const float* beta  = (const float*)d_in[7];
  const int*   mask  = (const int*)d_in[8];    // [16]
  float* out = (float*)d_out;

  // Workspace (81.9 MiB):
  //  [0,64M)      hs_bf bf16
  //  [64M,+4M)    Wc fp32
  //  [+4M,+10M)   Weff bf16 [5][1024][1024]; first 8.5 MB double as
  //               Whi/Wlo/WhiT/WloT + lApad hi/lo (dead before K3 writes).
  //  tail         A2 (80K), beff (20K)
  char* wsb = (char*)d_ws;
  u16*   hs_bf = (u16*)wsb;
  float* Wc    = (float*)(wsb + 67108864);
  u16*   weff  = (u16*)(wsb + 71303168);
  u16*   Whi   = weff;
  u16*   Wlo   = weff + 1048576;
  u16*   WhiT  = weff + 2097152;
  u16*   WloT  = weff + 3145728;
  u16*   lAh   = weff + 4194304;
  u16*   lAl   = weff + 4325376;
  float* A2    = (float*)(wsb + 81788928);
  float* beff  = (float*)(wsb + 81871360);

  k1_prep<<<1032 + CVT1_BLKS, 256, 0, stream>>>(
      hs, hs_bf, W, Whi, Wlo, WhiT, WloT, lA, lAh, lAl);
  k2_s2<<<272 + CVT2_BLKS, 256, 0, stream>>>(
      Whi, Wlo, WhiT, WloT, lAh, lAl, hs, hs_bf, Wc, A2);
  k3_weff<<<5120 + CVT3_BLKS, 256, 0, stream>>>(
      Wc, A2, lB, lA, W, b, hs, hs_bf, weff, beff);
  gemm_main<<<512, 512, 0, stream>>>(hs_bf, weff, beff, mask, out);
  ln4<<<M_TOT / 4, 256, 0, stream>>>(out, inp, gamma, beta);
}

// Round 13
// 464.125 us; speedup vs baseline: 1.0427x; 1.0427x over previous
//
#include <hip/hip_runtime.h>
#include <hip/hip_bf16.h>
#include <stdint.h>

// JinaEmbeddingsV3SelfOutput, algebraically folded:
//   h2 = hs @ Weff_t^T + beff_t,   Weff_t = W@W + 0.25*B_t@(A_t@W)  [per task]
//   beff_t = W@b + b + 0.25*B_t@(A_t@b)
//   out = LN(h2 + input)
// R13 = R11 (best, 478.6us) + bf16-h2: gemm stores h2 as bf16 into the FIRST
//   2048 B of each row's 4096 B slot in d_out (row pitch preserved -> no
//   cross-row alias, no extra workspace); ln4 reads its own row's bf16 h2 to
//   regs then overwrites the slot with the final fp32 row. Saves the 128 MB
//   fp32 h2 round-trip (64 W + 64 R). R12's deep-asm cvt reverted to R11's
//   one-shot (6th null: replay times for streaming kernels are not faithful;
//   only total dur_us is trusted now).
#define D_HID 1024
#define M_TOT 32768
#define LN_EPS 1e-5f

typedef __bf16 bf16x8 __attribute__((ext_vector_type(8)));
typedef float f32x4 __attribute__((ext_vector_type(4)));
typedef unsigned short u16;
typedef u16 u16x8 __attribute__((ext_vector_type(8)));
typedef u16 u16x4v __attribute__((ext_vector_type(4)));

__device__ __forceinline__ float bf2f(u16 x) {
  union { unsigned int u; float f; } c; c.u = ((unsigned int)x) << 16; return c.f;
}
__device__ __forceinline__ u16 f2bf(float f) {
  union { __bf16 h; u16 u; } c; c.h = (__bf16)f; return c.u;  // RNE
}
// Async global->LDS, 16B/lane. LDS dest is wave-uniform base + lane*16.
__device__ __forceinline__ void gld16(const u16* g, u16* lds_wave_base) {
  __builtin_amdgcn_global_load_lds(
      (__attribute__((address_space(1))) unsigned int*)g,
      (__attribute__((address_space(3))) unsigned int*)lds_wave_base, 16, 0, 0);
}

// one-shot cvt job: thread converts 8 fp32 -> 8 bf16 (R11 version).
__device__ __forceinline__ void cvt_job(const float* __restrict__ hs,
                                        u16* __restrict__ hs_bf, size_t idx) {
  const float4 a = *(const float4*)(hs + idx * 8);
  const float4 b = *(const float4*)(hs + idx * 8 + 4);
  u16x8 o;
  o[0] = f2bf(a.x); o[1] = f2bf(a.y); o[2] = f2bf(a.z); o[3] = f2bf(a.w);
  o[4] = f2bf(b.x); o[5] = f2bf(b.y); o[6] = f2bf(b.z); o[7] = f2bf(b.w);
  *(u16x8*)(hs_bf + idx * 8) = o;
}

// cvt slice bounds (thread-jobs of 8 elems; total 32768*1024/8 = 4194304)
#define CVT_K1_BLKS 5440
#define CVT_K2_BLKS 5472
#define CVT_K3_BLKS 5472
#define CVT_K2_OFF  (CVT_K1_BLKS * 256)                    // 1392640
#define CVT_K3_OFF  ((CVT_K1_BLKS + CVT_K2_BLKS) * 256)    // 2793472

// ---- K1: W split+transpose (0..1023), lA zero-pad split (1024..1031),
//          cvt slice (1032..6471) ----
__global__ __launch_bounds__(256) void k1_prep(
    const float* __restrict__ hs, u16* __restrict__ hs_bf,
    const float* __restrict__ W, u16* __restrict__ hi, u16* __restrict__ lo,
    u16* __restrict__ hiT, u16* __restrict__ loT,
    const float* __restrict__ lA, u16* __restrict__ lAh, u16* __restrict__ lAl) {
  __shared__ float tile[32][33];
  const int bid = blockIdx.x, tid = threadIdx.x;
  if (bid >= 1032) {
    cvt_job(hs, hs_bf, (size_t)(bid - 1032) * 256 + tid);
    return;
  }
  if (bid >= 1024) {                  // lA pad+split: 128x1024, rows >=20 zero
    const int b = bid - 1024;
    for (int i = tid; i < 16 * 1024; i += 256) {
      const int r = b * 16 + (i >> 10), c = i & 1023;
      const float v = (r < 20) ? lA[(size_t)r * 1024 + c] : 0.f;
      const u16 h = f2bf(v);
      lAh[(size_t)r * 1024 + c] = h;
      lAl[(size_t)r * 1024 + c] = f2bf(v - bf2f(h));
    }
    return;
  }
  const int bj = bid & 31, bi = bid >> 5;
  const int tx = tid & 31, ty = tid >> 5;
#pragma unroll
  for (int r0 = 0; r0 < 32; r0 += 8) {
    const int r = r0 + ty;
    const size_t o = (size_t)(bi * 32 + r) * D_HID + bj * 32 + tx;
    const float v = W[o];
    tile[r][tx] = v;
    const u16 h = f2bf(v);
    hi[o] = h; lo[o] = f2bf(v - bf2f(h));
  }
  __syncthreads();
#pragma unroll
  for (int r0 = 0; r0 < 32; r0 += 8) {
    const int r = r0 + ty;
    const float v = tile[tx][r];
    const size_t o = (size_t)(bj * 32 + r) * D_HID + bi * 32 + tx;
    const u16 h = f2bf(v);
    hiT[o] = h; loT[o] = f2bf(v - bf2f(h));
  }
}

// ---- K2: [W; lApad] @ W split-bf16 MFMA 64x64 (0..271) + cvt slice (272..5743) ----
__global__ __launch_bounds__(256) void k2_s2(
    const u16* __restrict__ Ah, const u16* __restrict__ Al,
    const u16* __restrict__ Bh, const u16* __restrict__ Bl,
    const u16* __restrict__ lAh, const u16* __restrict__ lAl,
    const float* __restrict__ hs, u16* __restrict__ hs_bf,
    float* __restrict__ C, float* __restrict__ A2) {
  __shared__ __align__(16) u16 smem[4][64 * 32];   // Ah,Al,Bh,Bl tiles
  const int bid = blockIdx.x, tid = threadIdx.x;
  if (bid >= 272) {
    cvt_job(hs, hs_bf, (size_t)CVT_K2_OFF + (size_t)(bid - 272) * 256 + tid);
    return;
  }
  const int wave = tid >> 6, lane = tid & 63;
  const int by = bid >> 4, bx = bid & 15;
  const bool isA2 = (by == 16);
  const u16* Asel_h = isA2 ? lAh : Ah;
  const u16* Asel_l = isA2 ? lAl : Al;
  const int arow0 = isA2 ? 0 : by * 64;
  const u16* gsel = (wave == 0) ? Asel_h : (wave == 1) ? Asel_l
                  : (wave == 2) ? Bh : Bl;
  const int rb = (wave < 2) ? arow0 : bx * 64;
  const u16* gp = gsel + (size_t)(rb + (lane >> 2)) * D_HID + (lane & 3) * 8;
  u16* sb = &smem[wave][0];

  const int l15 = lane & 15, quad = lane >> 4;
  const int wm = wave >> 1, wn = wave & 1;
  const int fA = (wm * 32 + l15) * 32 + quad * 8;
  const int fB = (wn * 32 + l15) * 32 + quad * 8;
  f32x4 acc[2][2];
#pragma unroll
  for (int m = 0; m < 2; ++m)
#pragma unroll
    for (int n = 0; n < 2; ++n) acc[m][n] = (f32x4){0.f, 0.f, 0.f, 0.f};

  for (int k0 = 0; k0 < D_HID; k0 += 32) {
    __syncthreads();
#pragma unroll
    for (int q = 0; q < 4; ++q)
      gld16(gp + (size_t)q * 16 * D_HID, sb + q * 512);
    gp += 32;
    __syncthreads();
    bf16x8 ahf[2], alf[2], bhf[2], blf[2];
#pragma unroll
    for (int m = 0; m < 2; ++m) {
      ahf[m] = *(const bf16x8*)(&smem[0][fA + m * 512]);
      alf[m] = *(const bf16x8*)(&smem[1][fA + m * 512]);
    }
#pragma unroll
    for (int n = 0; n < 2; ++n) {
      bhf[n] = *(const bf16x8*)(&smem[2][fB + n * 512]);
      blf[n] = *(const bf16x8*)(&smem[3][fB + n * 512]);
    }
#pragma unroll
    for (int m = 0; m < 2; ++m)
#pragma unroll
      for (int n = 0; n < 2; ++n) {
        acc[m][n] = __builtin_amdgcn_mfma_f32_16x16x32_bf16(ahf[m], bhf[n], acc[m][n], 0, 0, 0);
        acc[m][n] = __builtin_amdgcn_mfma_f32_16x16x32_bf16(alf[m], bhf[n], acc[m][n], 0, 0, 0);
        acc[m][n] = __builtin_amdgcn_mfma_f32_16x16x32_bf16(ahf[m], blf[n], acc[m][n], 0, 0, 0);
      }
  }
  const int nn0 = bx * 64 + wn * 32;
#pragma unroll
  for (int m = 0; m < 2; ++m)
#pragma unroll
    for (int n = 0; n < 2; ++n) {
      const int nn = nn0 + n * 16 + l15;
#pragma unroll
      for (int r = 0; r < 4; ++r) {
        const int lr = wm * 32 + m * 16 + quad * 4 + r;
        if (!isA2) {
          C[(size_t)(by * 64 + lr) * D_HID + nn] = acc[m][n][r];
        } else if (lr < 20) {
          A2[(size_t)lr * D_HID + nn] = acc[m][n][r];
        }
      }
    }
}

// ---- K3: weff+beff (0..5119, n=bid&1023 t=bid>>10) + cvt (5120..10591) ----
__global__ __launch_bounds__(256) void k3_weff(
    const float* __restrict__ Wc, const float* __restrict__ A2,
    const float* __restrict__ lB, const float* __restrict__ lA,
    const float* __restrict__ W, const float* __restrict__ bvec,
    const float* __restrict__ hs, u16* __restrict__ hs_bf,
    u16* __restrict__ Weff, float* __restrict__ beff) {
  const int bid = blockIdx.x, tid = threadIdx.x;
  if (bid >= 5120) {
    cvt_job(hs, hs_bf, (size_t)CVT_K3_OFF + (size_t)(bid - 5120) * 256 + tid);
    return;
  }
  const int n = bid & 1023, t = bid >> 10;
  const int wave = tid >> 6, lane = tid & 63;
  float br[4];
#pragma unroll
  for (int r = 0; r < 4; ++r) br[r] = lB[(size_t)t * 4096 + n * 4 + r];
  float4 v = *(const float4*)(Wc + (size_t)n * D_HID + tid * 4);
#pragma unroll
  for (int r = 0; r < 4; ++r) {
    const float4 a2 = *(const float4*)(A2 + (size_t)(t * 4 + r) * D_HID + tid * 4);
    const float s = 0.25f * br[r];
    v.x += s * a2.x; v.y += s * a2.y; v.z += s * a2.z; v.w += s * a2.w;
  }
  u16x4v o; o[0] = f2bf(v.x); o[1] = f2bf(v.y); o[2] = f2bf(v.z); o[3] = f2bf(v.w);
  *(u16x4v*)(Weff + (size_t)t * 1048576 + (size_t)n * D_HID + tid * 4) = o;
  const float4 bb = *(const float4*)(bvec + tid * 4);
  float p[5];
  {
    const float4 wr = *(const float4*)(W + (size_t)n * D_HID + tid * 4);
    p[0] = wr.x * bb.x + wr.y * bb.y + wr.z * bb.z + wr.w * bb.w;
  }
#pragma unroll
  for (int r = 0; r < 4; ++r) {
    const float4 ar = *(const float4*)(lA + (size_t)(t * 4 + r) * D_HID + tid * 4);
    p[1 + r] = ar.x * bb.x + ar.y * bb.y + ar.z * bb.z + ar.w * bb.w;
  }
#pragma unroll
  for (int m = 1; m < 64; m <<= 1)
#pragma unroll
    for (int jj = 0; jj < 5; ++jj) p[jj] += __shfl_xor(p[jj], m);
  __shared__ float red[4][5];
  if (lane == 0)
#pragma unroll
    for (int jj = 0; jj < 5; ++jj) red[wave][jj] = p[jj];
  __syncthreads();
  if (tid == 0) {
    float P = 0.f, Cr[4] = {0.f, 0.f, 0.f, 0.f};
#pragma unroll
    for (int w = 0; w < 4; ++w) {
      P += red[w][0];
#pragma unroll
      for (int r = 0; r < 4; ++r) Cr[r] += red[w][1 + r];
    }
    const float e = br[0]*Cr[0] + br[1]*Cr[1] + br[2]*Cr[2] + br[3]*Cr[3];
    beff[t * D_HID + n] = P + bvec[n] + 0.25f * e;
  }
}

// ---- main GEMM: h2 = hs_bf @ Weff[task]^T + beff, stored as BF16 into the
//      first 2048 B of each row's 4096 B slot in d_out (row pitch preserved;
//      halves h2 write traffic). Schedule: 256x256, BK=64, 8 waves, 128 KB
//      dbuf, 8-phase counted-vmcnt + XOR octet swizzle (R10/R11 verbatim). ----
__global__ __launch_bounds__(512, 1) void gemm_main(
    const u16* __restrict__ Ag, const u16* __restrict__ Wf,
    const float* __restrict__ beff, const int* __restrict__ mask,
    u16* __restrict__ outb) {
  __shared__ __align__(16) u16 sAf[2 * 16384];
  __shared__ __align__(16) u16 sBf[2 * 16384];
  const int tid = threadIdx.x, wave = tid >> 6, lane = tid & 63;
  const int L = blockIdx.x;                 // 512 blocks
  const int xcd = L & 7, j = L >> 3;
  const int bx = j & 3;                     // N-tile 0..3
  const int by = xcd * 16 + (j >> 2);       // M-tile 0..127; XCD-clustered
  const int task = mask[by >> 3];           // 256-row tile never crosses batch
  const u16* Bg = Wf + (size_t)task * (D_HID * D_HID);

  const int acol = ((lane & 7) ^ (lane >> 3)) * 8;
  const int aBase = (by * 256 + wave * 8 + (lane >> 3)) * D_HID + acol;
  const int bBase = (bx * 256 + wave * 8 + (lane >> 3)) * D_HID + acol;

  auto stageA = [&](int ktar, int half) {
#pragma unroll
    for (int q = 0; q < 2; ++q)
      gld16(Ag + (aBase + ktar * 64 + half * 131072 + q * 65536),
            sAf + ((ktar & 1) * 16384 + half * 8192 + q * 4096 + wave * 512));
  };
  auto stageB = [&](int ktar, int half) {
#pragma unroll
    for (int q = 0; q < 2; ++q)
      gld16(Bg + (bBase + ktar * 64 + half * 131072 + q * 65536),
            sBf + ((ktar & 1) * 16384 + half * 8192 + q * 4096 + wave * 512));
  };

  const int wm = wave >> 2, wn = wave & 3;
  const int l15 = lane & 15, quad = lane >> 4, l7 = lane & 7;
  const int vA0 = (wm * 128 + l15) * 64 + ((quad ^ l7) * 8);
  const int vB0 = (wn * 64 + l15) * 64 + ((quad ^ l7) * 8);

  f32x4 acc[8][4];
#pragma unroll
  for (int i = 0; i < 8; ++i)
#pragma unroll
    for (int jn = 0; jn < 4; ++jn) acc[i][jn] = (f32x4){0.f, 0.f, 0.f, 0.f};

  stageB(0, 0); stageB(0, 1); stageA(0, 0); stageA(0, 1);
  stageB(1, 0); stageA(1, 0);
  asm volatile("s_waitcnt vmcnt(4)" ::: "memory");
  __builtin_amdgcn_s_barrier();
  __builtin_amdgcn_sched_barrier(0);

  bf16x8 a[4][2], b[4][2];
#pragma unroll 1
  for (int k2 = 0; k2 < 8; ++k2) {
#pragma unroll
    for (int par = 0; par < 2; ++par) {
      const int kt = k2 * 2 + par;
      const u16* pA = sAf + par * 16384;
      const u16* pB = sBf + par * 16384;
      const bool st01 = (par == 0) || (k2 < 7);  // kt < 15
      const bool st23 = (k2 < 7);                // kt < 14

      // -------- phase 0: (qm0, qn0) --------
#pragma unroll
      for (int m4 = 0; m4 < 4; ++m4) {
        a[m4][0] = *(const bf16x8*)(pA + (vA0 + m4 * 1024));
        a[m4][1] = *(const bf16x8*)(pA + ((vA0 ^ 32) + m4 * 1024));
      }
#pragma unroll
      for (int n2 = 0; n2 < 2; ++n2) {
        b[n2][0] = *(const bf16x8*)(pB + (vB0 + n2 * 1024));
        b[n2][1] = *(const bf16x8*)(pB + ((vB0 ^ 32) + n2 * 1024));
      }
      if (st01) stageB(kt + 1, 1);
      __builtin_amdgcn_s_barrier();
      asm volatile("s_waitcnt lgkmcnt(0)" ::: "memory");
      __builtin_amdgcn_sched_barrier(0);
      __builtin_amdgcn_s_setprio(1);
#pragma unroll
      for (int m4 = 0; m4 < 4; ++m4)
#pragma unroll
        for (int n2 = 0; n2 < 2; ++n2)
#pragma unroll
          for (int kk = 0; kk < 2; ++kk)
            acc[m4][n2] = __builtin_amdgcn_mfma_f32_16x16x32_bf16(
                a[m4][kk], b[n2][kk], acc[m4][n2], 0, 0, 0);
      __builtin_amdgcn_s_setprio(0);
      __builtin_amdgcn_s_barrier();
      __builtin_amdgcn_sched_barrier(0);

      // -------- phase 1: (qm0, qn1) --------
#pragma unroll
      for (int n2 = 0; n2 < 2; ++n2) {
        b[2 + n2][0] = *(const bf16x8*)(pB + (vB0 + (2 + n2) * 1024));
        b[2 + n2][1] = *(const bf16x8*)(pB + ((vB0 ^ 32) + (2 + n2) * 1024));
      }
      if (st01) stageA(kt + 1, 1);
      __builtin_amdgcn_s_barrier();
      asm volatile("s_waitcnt lgkmcnt(0)" ::: "memory");
      __builtin_amdgcn_sched_barrier(0);
      __builtin_amdgcn_s_setprio(1);
#pragma unroll
      for (int m4 = 0; m4 < 4; ++m4)
#pragma unroll
        for (int n2 = 0; n2 < 2; ++n2)
#pragma unroll
          for (int kk = 0; kk < 2; ++kk)
            acc[m4][2 + n2] = __builtin_amdgcn_mfma_f32_16x16x32_bf16(
                a[m4][kk], b[2 + n2][kk], acc[m4][2 + n2], 0, 0, 0);
      __builtin_amdgcn_s_setprio(0);
      __builtin_amdgcn_s_barrier();
      __builtin_amdgcn_sched_barrier(0);

      // -------- phase 2: (qm1, qn0) --------
#pragma unroll
      for (int m4 = 0; m4 < 4; ++m4) {
        a[m4][0] = *(const bf16x8*)(pA + (vA0 + (4 + m4) * 1024));
        a[m4][1] = *(const bf16x8*)(pA + ((vA0 ^ 32) + (4 + m4) * 1024));
      }
      if (st23) stageB(kt + 2, 0);
      __builtin_amdgcn_s_barrier();
      asm volatile("s_waitcnt lgkmcnt(0)" ::: "memory");
      __builtin_amdgcn_sched_barrier(0);
      __builtin_amdgcn_s_setprio(1);
#pragma unroll
      for (int m4 = 0; m4 < 4; ++m4)
#pragma unroll
        for (int n2 = 0; n2 < 2; ++n2)
#pragma unroll
          for (int kk = 0; kk < 2; ++kk)
            acc[4 + m4][n2] = __builtin_amdgcn_mfma_f32_16x16x32_bf16(
                a[m4][kk], b[n2][kk], acc[4 + m4][n2], 0, 0, 0);
      __builtin_amdgcn_s_setprio(0);
      __builtin_amdgcn_s_barrier();
      __builtin_amdgcn_sched_barrier(0);

      // -------- phase 3: (qm1, qn1) --------
      if (st23) stageA(kt + 2, 0);
      if (par == 0) {
        if (k2 < 7) { asm volatile("s_waitcnt vmcnt(4)" ::: "memory"); }
        else        { asm volatile("s_waitcnt vmcnt(0)" ::: "memory"); }
      } else {
        if (k2 < 7) { asm volatile("s_waitcnt vmcnt(4)" ::: "memory"); }
      }
      __builtin_amdgcn_s_barrier();
      asm volatile("s_waitcnt lgkmcnt(0)" ::: "memory");
      __builtin_amdgcn_sched_barrier(0);
      __builtin_amdgcn_s_setprio(1);
#pragma unroll
      for (int m4 = 0; m4 < 4; ++m4)
#pragma unroll
        for (int n2 = 0; n2 < 2; ++n2)
#pragma unroll
          for (int kk = 0; kk < 2; ++kk)
            acc[4 + m4][2 + n2] = __builtin_amdgcn_mfma_f32_16x16x32_bf16(
                a[m4][kk], b[2 + n2][kk], acc[4 + m4][2 + n2], 0, 0, 0);
      __builtin_amdgcn_s_setprio(0);
      __builtin_amdgcn_s_barrier();
      __builtin_amdgcn_sched_barrier(0);
    }
  }

  // epilogue: h2 = acc + beff, stored BF16 at row pitch 2048 u16 (= 4096 B).
  // C/D: col=lane&15, row=quad*4+r.
  const float* bb = beff + task * D_HID;
  const size_t mBase = (size_t)by * 256 + wm * 128;
  const int nb0 = bx * 256 + wn * 64;
#pragma unroll
  for (int mf = 0; mf < 8; ++mf)
#pragma unroll
    for (int nf = 0; nf < 4; ++nf) {
      const int n = nb0 + nf * 16 + l15;
      const float bval = bb[n];
#pragma unroll
      for (int r = 0; r < 4; ++r) {
        const size_t m = mBase + mf * 16 + quad * 4 + r;
        outb[m * 2048 + n] = f2bf(acc[mf][nf][r] + bval);
      }
    }
}

// ---- ln4: out = LN(bf16(h2) + resid). h2 bf16 lives in the first 2048 B of
//      each 4096 B out-row slot; wave loads its OWN row to regs, then
//      overwrites the slot with the fp32 result (read-before-write, no race).
__global__ __launch_bounds__(256) void ln4(float* __restrict__ out,
                                           const float* __restrict__ resid,
                                           const float* __restrict__ gamma,
                                           const float* __restrict__ beta) {
  const int row = blockIdx.x * 4 + (threadIdx.x >> 6);
  const int lane = threadIdx.x & 63;
  const u16* hb = (const u16*)out + (size_t)row * 2048;
  const float* rp = resid + (size_t)row * D_HID;
  float* po = out + (size_t)row * D_HID;
  float4 v[4];
#pragma unroll
  for (int k = 0; k < 4; ++k) {
    const int c = lane * 4 + k * 256;
    const u16x4v h = *(const u16x4v*)(hb + c);
    const float4 r = *(const float4*)(rp + c);
    v[k].x = bf2f(h[0]) + r.x; v[k].y = bf2f(h[1]) + r.y;
    v[k].z = bf2f(h[2]) + r.z; v[k].w = bf2f(h[3]) + r.w;
  }
  float s = 0.f, q = 0.f;
#pragma unroll
  for (int k = 0; k < 4; ++k) {
    s += v[k].x + v[k].y + v[k].z + v[k].w;
    q += v[k].x * v[k].x + v[k].y * v[k].y + v[k].z * v[k].z + v[k].w * v[k].w;
  }
#pragma unroll
  for (int m = 1; m < 64; m <<= 1) { s += __shfl_xor(s, m); q += __shfl_xor(q, m); }
  const float mu  = s * (1.f / (float)D_HID);
  const float var = q * (1.f / (float)D_HID) - mu * mu;
  const float inv = rsqrtf(var + LN_EPS);
#pragma unroll
  for (int k = 0; k < 4; ++k) {
    const int c = lane * 4 + k * 256;
    const float4 g  = *(const float4*)(gamma + c);
    const float4 bb = *(const float4*)(beta + c);
    float4 o;
    o.x = (v[k].x - mu) * inv * g.x + bb.x;
    o.y = (v[k].y - mu) * inv * g.y + bb.y;
    o.z = (v[k].z - mu) * inv * g.z + bb.z;
    o.w = (v[k].w - mu) * inv * g.w + bb.w;
    *(float4*)(po + c) = o;
  }
}

extern "C" void kernel_launch(void* const* d_in, const int* in_sizes, int n_in,
                              void* d_out, int out_size, void* d_ws, size_t ws_size,
                              hipStream_t stream) {
  const float* hs    = (const float*)d_in[0];  // [16,2048,1024] fp32
  const float* inp   = (const float*)d_in[1];  // [16,2048,1024] fp32
  const float* W     = (const float*)d_in[2];  // [1024,1024] fp32
  const float* b     = (const float*)d_in[3];  // [1024]
  const float* lA    = (const float*)d_in[4];  // [5,4,1024]
  const float* lB    = (const float*)d_in[5];  // [5,1024,4]
  const float* gamma = (const float*)d_in[6];
  const float* beta  = (const float*)d_in[7];
  const int*   mask  = (const int*)d_in[8];    // [16]
  float* out = (float*)d_out;

  // Workspace (81.9 MiB):
  //  [0,64M)      hs_bf bf16
  //  [64M,+4M)    Wc fp32
  //  [+4M,+10M)   Weff bf16 [5][1024][1024]; first 8.5 MB double as
  //               Whi/Wlo/WhiT/WloT + lApad hi/lo (dead before K3 writes).
  //  tail         A2 (80K), beff (20K)
  char* wsb = (char*)d_ws;
  u16*   hs_bf = (u16*)wsb;
  float* Wc    = (float*)(wsb + 67108864);
  u16*   weff  = (u16*)(wsb + 71303168);
  u16*   Whi   = weff;
  u16*   Wlo   = weff + 1048576;
  u16*   WhiT  = weff + 2097152;
  u16*   WloT  = weff + 3145728;
  u16*   lAh   = weff + 4194304;
  u16*   lAl   = weff + 4325376;
  float* A2    = (float*)(wsb + 81788928);
  float* beff  = (float*)(wsb + 81871360);

  k1_prep<<<1032 + CVT_K1_BLKS, 256, 0, stream>>>(
      hs, hs_bf, W, Whi, Wlo, WhiT, WloT, lA, lAh, lAl);
  k2_s2<<<272 + CVT_K2_BLKS, 256, 0, stream>>>(
      Whi, Wlo, WhiT, WloT, lAh, lAl, hs, hs_bf, Wc, A2);
  k3_weff<<<5120 + CVT_K3_BLKS, 256, 0, stream>>>(
      Wc, A2, lB, lA, W, b, hs, hs_bf, weff, beff);
  gemm_main<<<512, 512, 0, stream>>>(hs_bf, weff, beff, mask, (u16*)out);
  ln4<<<M_TOT / 4, 256, 0, stream>>>(out, inp, gamma, beta);
}

// Round 14
// 461.789 us; speedup vs baseline: 1.0480x; 1.0051x over previous
//
#include <hip/hip_runtime.h>
#include <hip/hip_bf16.h>
#include <stdint.h>

// JinaEmbeddingsV3SelfOutput, algebraically folded:
//   h2 = hs @ Weff_t^T + beff_t,   Weff_t = W@W + 0.25*B_t@(A_t@W)  [per task]
//   beff_t = W@b + b + 0.25*B_t@(A_t@b)
//   out = LN(h2 + input)
// R14 = R13 + gemm_main prefetch-lead rebalance (pure reorder, same LDS):
//   old leads: A(kt+1,1)=2 phases (~350cy << ~900-2000cy loaded HBM latency
//   -> vmcnt stalled every K-tile), B(kt+1,1)=3. Buffer-lifetime analysis:
//   A-reads of tile kt all complete by ph2 exit-barrier, B-reads by ph1
//   exit-barrier (ph3 consumes regs only) -> both A(kt+2) halves can be
//   issued at ph3(kt), both B(kt+2) halves at ph2(kt). New leads: A=4, B=5
//   phases uniform. vmcnt: newer-than-tile-(kt+1) = B(kt+2)^4 + A(kt+2)^4
//   = 8 -> vmcnt(8) at ph3 (kt<14); vmcnt(0) at kt==14; none at kt==15.
//   Prologue: stage tiles 0+1 (16 loads), vmcnt(8).
#define D_HID 1024
#define M_TOT 32768
#define LN_EPS 1e-5f

typedef __bf16 bf16x8 __attribute__((ext_vector_type(8)));
typedef float f32x4 __attribute__((ext_vector_type(4)));
typedef unsigned short u16;
typedef u16 u16x8 __attribute__((ext_vector_type(8)));
typedef u16 u16x4v __attribute__((ext_vector_type(4)));

__device__ __forceinline__ float bf2f(u16 x) {
  union { unsigned int u; float f; } c; c.u = ((unsigned int)x) << 16; return c.f;
}
__device__ __forceinline__ u16 f2bf(float f) {
  union { __bf16 h; u16 u; } c; c.h = (__bf16)f; return c.u;  // RNE
}
// Async global->LDS, 16B/lane. LDS dest is wave-uniform base + lane*16.
__device__ __forceinline__ void gld16(const u16* g, u16* lds_wave_base) {
  __builtin_amdgcn_global_load_lds(
      (__attribute__((address_space(1))) unsigned int*)g,
      (__attribute__((address_space(3))) unsigned int*)lds_wave_base, 16, 0, 0);
}

// one-shot cvt job: thread converts 8 fp32 -> 8 bf16 (proven-best shape).
__device__ __forceinline__ void cvt_job(const float* __restrict__ hs,
                                        u16* __restrict__ hs_bf, size_t idx) {
  const float4 a = *(const float4*)(hs + idx * 8);
  const float4 b = *(const float4*)(hs + idx * 8 + 4);
  u16x8 o;
  o[0] = f2bf(a.x); o[1] = f2bf(a.y); o[2] = f2bf(a.z); o[3] = f2bf(a.w);
  o[4] = f2bf(b.x); o[5] = f2bf(b.y); o[6] = f2bf(b.z); o[7] = f2bf(b.w);
  *(u16x8*)(hs_bf + idx * 8) = o;
}

// cvt slice bounds (thread-jobs of 8 elems; total 32768*1024/8 = 4194304)
#define CVT_K1_BLKS 5440
#define CVT_K2_BLKS 5472
#define CVT_K3_BLKS 5472
#define CVT_K2_OFF  (CVT_K1_BLKS * 256)                    // 1392640
#define CVT_K3_OFF  ((CVT_K1_BLKS + CVT_K2_BLKS) * 256)    // 2793472

// ---- K1: W split+transpose (0..1023), lA zero-pad split (1024..1031),
//          cvt slice (1032..6471) ----
__global__ __launch_bounds__(256) void k1_prep(
    const float* __restrict__ hs, u16* __restrict__ hs_bf,
    const float* __restrict__ W, u16* __restrict__ hi, u16* __restrict__ lo,
    u16* __restrict__ hiT, u16* __restrict__ loT,
    const float* __restrict__ lA, u16* __restrict__ lAh, u16* __restrict__ lAl) {
  __shared__ float tile[32][33];
  const int bid = blockIdx.x, tid = threadIdx.x;
  if (bid >= 1032) {
    cvt_job(hs, hs_bf, (size_t)(bid - 1032) * 256 + tid);
    return;
  }
  if (bid >= 1024) {                  // lA pad+split: 128x1024, rows >=20 zero
    const int b = bid - 1024;
    for (int i = tid; i < 16 * 1024; i += 256) {
      const int r = b * 16 + (i >> 10), c = i & 1023;
      const float v = (r < 20) ? lA[(size_t)r * 1024 + c] : 0.f;
      const u16 h = f2bf(v);
      lAh[(size_t)r * 1024 + c] = h;
      lAl[(size_t)r * 1024 + c] = f2bf(v - bf2f(h));
    }
    return;
  }
  const int bj = bid & 31, bi = bid >> 5;
  const int tx = tid & 31, ty = tid >> 5;
#pragma unroll
  for (int r0 = 0; r0 < 32; r0 += 8) {
    const int r = r0 + ty;
    const size_t o = (size_t)(bi * 32 + r) * D_HID + bj * 32 + tx;
    const float v = W[o];
    tile[r][tx] = v;
    const u16 h = f2bf(v);
    hi[o] = h; lo[o] = f2bf(v - bf2f(h));
  }
  __syncthreads();
#pragma unroll
  for (int r0 = 0; r0 < 32; r0 += 8) {
    const int r = r0 + ty;
    const float v = tile[tx][r];
    const size_t o = (size_t)(bj * 32 + r) * D_HID + bi * 32 + tx;
    const u16 h = f2bf(v);
    hiT[o] = h; loT[o] = f2bf(v - bf2f(h));
  }
}

// ---- K2: [W; lApad] @ W split-bf16 MFMA 64x64 (0..271) + cvt slice (272..5743) ----
__global__ __launch_bounds__(256) void k2_s2(
    const u16* __restrict__ Ah, const u16* __restrict__ Al,
    const u16* __restrict__ Bh, const u16* __restrict__ Bl,
    const u16* __restrict__ lAh, const u16* __restrict__ lAl,
    const float* __restrict__ hs, u16* __restrict__ hs_bf,
    float* __restrict__ C, float* __restrict__ A2) {
  __shared__ __align__(16) u16 smem[4][64 * 32];   // Ah,Al,Bh,Bl tiles
  const int bid = blockIdx.x, tid = threadIdx.x;
  if (bid >= 272) {
    cvt_job(hs, hs_bf, (size_t)CVT_K2_OFF + (size_t)(bid - 272) * 256 + tid);
    return;
  }
  const int wave = tid >> 6, lane = tid & 63;
  const int by = bid >> 4, bx = bid & 15;
  const bool isA2 = (by == 16);
  const u16* Asel_h = isA2 ? lAh : Ah;
  const u16* Asel_l = isA2 ? lAl : Al;
  const int arow0 = isA2 ? 0 : by * 64;
  const u16* gsel = (wave == 0) ? Asel_h : (wave == 1) ? Asel_l
                  : (wave == 2) ? Bh : Bl;
  const int rb = (wave < 2) ? arow0 : bx * 64;
  const u16* gp = gsel + (size_t)(rb + (lane >> 2)) * D_HID + (lane & 3) * 8;
  u16* sb = &smem[wave][0];

  const int l15 = lane & 15, quad = lane >> 4;
  const int wm = wave >> 1, wn = wave & 1;
  const int fA = (wm * 32 + l15) * 32 + quad * 8;
  const int fB = (wn * 32 + l15) * 32 + quad * 8;
  f32x4 acc[2][2];
#pragma unroll
  for (int m = 0; m < 2; ++m)
#pragma unroll
    for (int n = 0; n < 2; ++n) acc[m][n] = (f32x4){0.f, 0.f, 0.f, 0.f};

  for (int k0 = 0; k0 < D_HID; k0 += 32) {
    __syncthreads();
#pragma unroll
    for (int q = 0; q < 4; ++q)
      gld16(gp + (size_t)q * 16 * D_HID, sb + q * 512);
    gp += 32;
    __syncthreads();
    bf16x8 ahf[2], alf[2], bhf[2], blf[2];
#pragma unroll
    for (int m = 0; m < 2; ++m) {
      ahf[m] = *(const bf16x8*)(&smem[0][fA + m * 512]);
      alf[m] = *(const bf16x8*)(&smem[1][fA + m * 512]);
    }
#pragma unroll
    for (int n = 0; n < 2; ++n) {
      bhf[n] = *(const bf16x8*)(&smem[2][fB + n * 512]);
      blf[n] = *(const bf16x8*)(&smem[3][fB + n * 512]);
    }
#pragma unroll
    for (int m = 0; m < 2; ++m)
#pragma unroll
      for (int n = 0; n < 2; ++n) {
        acc[m][n] = __builtin_amdgcn_mfma_f32_16x16x32_bf16(ahf[m], bhf[n], acc[m][n], 0, 0, 0);
        acc[m][n] = __builtin_amdgcn_mfma_f32_16x16x32_bf16(alf[m], bhf[n], acc[m][n], 0, 0, 0);
        acc[m][n] = __builtin_amdgcn_mfma_f32_16x16x32_bf16(ahf[m], blf[n], acc[m][n], 0, 0, 0);
      }
  }
  const int nn0 = bx * 64 + wn * 32;
#pragma unroll
  for (int m = 0; m < 2; ++m)
#pragma unroll
    for (int n = 0; n < 2; ++n) {
      const int nn = nn0 + n * 16 + l15;
#pragma unroll
      for (int r = 0; r < 4; ++r) {
        const int lr = wm * 32 + m * 16 + quad * 4 + r;
        if (!isA2) {
          C[(size_t)(by * 64 + lr) * D_HID + nn] = acc[m][n][r];
        } else if (lr < 20) {
          A2[(size_t)lr * D_HID + nn] = acc[m][n][r];
        }
      }
    }
}

// ---- K3: weff+beff (0..5119, n=bid&1023 t=bid>>10) + cvt (5120..10591) ----
__global__ __launch_bounds__(256) void k3_weff(
    const float* __restrict__ Wc, const float* __restrict__ A2,
    const float* __restrict__ lB, const float* __restrict__ lA,
    const float* __restrict__ W, const float* __restrict__ bvec,
    const float* __restrict__ hs, u16* __restrict__ hs_bf,
    u16* __restrict__ Weff, float* __restrict__ beff) {
  const int bid = blockIdx.x, tid = threadIdx.x;
  if (bid >= 5120) {
    cvt_job(hs, hs_bf, (size_t)CVT_K3_OFF + (size_t)(bid - 5120) * 256 + tid);
    return;
  }
  const int n = bid & 1023, t = bid >> 10;
  const int wave = tid >> 6, lane = tid & 63;
  float br[4];
#pragma unroll
  for (int r = 0; r < 4; ++r) br[r] = lB[(size_t)t * 4096 + n * 4 + r];
  float4 v = *(const float4*)(Wc + (size_t)n * D_HID + tid * 4);
#pragma unroll
  for (int r = 0; r < 4; ++r) {
    const float4 a2 = *(const float4*)(A2 + (size_t)(t * 4 + r) * D_HID + tid * 4);
    const float s = 0.25f * br[r];
    v.x += s * a2.x; v.y += s * a2.y; v.z += s * a2.z; v.w += s * a2.w;
  }
  u16x4v o; o[0] = f2bf(v.x); o[1] = f2bf(v.y); o[2] = f2bf(v.z); o[3] = f2bf(v.w);
  *(u16x4v*)(Weff + (size_t)t * 1048576 + (size_t)n * D_HID + tid * 4) = o;
  const float4 bb = *(const float4*)(bvec + tid * 4);
  float p[5];
  {
    const float4 wr = *(const float4*)(W + (size_t)n * D_HID + tid * 4);
    p[0] = wr.x * bb.x + wr.y * bb.y + wr.z * bb.z + wr.w * bb.w;
  }
#pragma unroll
  for (int r = 0; r < 4; ++r) {
    const float4 ar = *(const float4*)(lA + (size_t)(t * 4 + r) * D_HID + tid * 4);
    p[1 + r] = ar.x * bb.x + ar.y * bb.y + ar.z * bb.z + ar.w * bb.w;
  }
#pragma unroll
  for (int m = 1; m < 64; m <<= 1)
#pragma unroll
    for (int jj = 0; jj < 5; ++jj) p[jj] += __shfl_xor(p[jj], m);
  __shared__ float red[4][5];
  if (lane == 0)
#pragma unroll
    for (int jj = 0; jj < 5; ++jj) red[wave][jj] = p[jj];
  __syncthreads();
  if (tid == 0) {
    float P = 0.f, Cr[4] = {0.f, 0.f, 0.f, 0.f};
#pragma unroll
    for (int w = 0; w < 4; ++w) {
      P += red[w][0];
#pragma unroll
      for (int r = 0; r < 4; ++r) Cr[r] += red[w][1 + r];
    }
    const float e = br[0]*Cr[0] + br[1]*Cr[1] + br[2]*Cr[2] + br[3]*Cr[3];
    beff[t * D_HID + n] = P + bvec[n] + 0.25f * e;
  }
}

// ---- main GEMM: h2 = hs_bf @ Weff[task]^T + beff, stored BF16 (R13).
// 256x256, BK=64, 8 waves, 128 KB dbuf, XOR octet swizzle. R14 schedule:
//   ph0: ds a(rows 0..63), b(nf 0-1); bar; lgkm; MFMA q00; bar.
//   ph1: ds b(nf 2-3); bar; lgkm; MFMA q01; bar.
//   ph2: ds a(rows 64..127); stage B(kt+2) BOTH halves; bar; lgkm; MFMA q10; bar.
//        (B-buf kt&1 fully consumed at ph1 exit-barrier -> overwrite safe)
//   ph3: stage A(kt+2) BOTH halves; vmcnt(8); bar; lgkm; MFMA q11; bar.
//        (A-buf kt&1 fully consumed at ph2 exit-barrier -> overwrite safe;
//         vmcnt(8) leaves exactly B(kt+2)^4+A(kt+2)^4 in flight -> all of
//         tile kt+1 landed; exit barrier globalizes before kt+1 ph0 reads)
// Leads: A=4 phases, B=5 (was A=2!). Tail: kt==14 vmcnt(0); kt==15 no wait.
__global__ __launch_bounds__(512, 1) void gemm_main(
    const u16* __restrict__ Ag, const u16* __restrict__ Wf,
    const float* __restrict__ beff, const int* __restrict__ mask,
    u16* __restrict__ outb) {
  __shared__ __align__(16) u16 sAf[2 * 16384];
  __shared__ __align__(16) u16 sBf[2 * 16384];
  const int tid = threadIdx.x, wave = tid >> 6, lane = tid & 63;
  const int L = blockIdx.x;                 // 512 blocks
  const int xcd = L & 7, j = L >> 3;
  const int bx = j & 3;                     // N-tile 0..3
  const int by = xcd * 16 + (j >> 2);       // M-tile 0..127; XCD-clustered
  const int task = mask[by >> 3];           // 256-row tile never crosses batch
  const u16* Bg = Wf + (size_t)task * (D_HID * D_HID);

  const int acol = ((lane & 7) ^ (lane >> 3)) * 8;
  const int aBase = (by * 256 + wave * 8 + (lane >> 3)) * D_HID + acol;
  const int bBase = (bx * 256 + wave * 8 + (lane >> 3)) * D_HID + acol;

  auto stageA = [&](int ktar, int half) {
#pragma unroll
    for (int q = 0; q < 2; ++q)
      gld16(Ag + (aBase + ktar * 64 + half * 131072 + q * 65536),
            sAf + ((ktar & 1) * 16384 + half * 8192 + q * 4096 + wave * 512));
  };
  auto stageB = [&](int ktar, int half) {
#pragma unroll
    for (int q = 0; q < 2; ++q)
      gld16(Bg + (bBase + ktar * 64 + half * 131072 + q * 65536),
            sBf + ((ktar & 1) * 16384 + half * 8192 + q * 4096 + wave * 512));
  };

  const int wm = wave >> 2, wn = wave & 3;
  const int l15 = lane & 15, quad = lane >> 4, l7 = lane & 7;
  const int vA0 = (wm * 128 + l15) * 64 + ((quad ^ l7) * 8);
  const int vB0 = (wn * 64 + l15) * 64 + ((quad ^ l7) * 8);

  f32x4 acc[8][4];
#pragma unroll
  for (int i = 0; i < 8; ++i)
#pragma unroll
    for (int jn = 0; jn < 4; ++jn) acc[i][jn] = (f32x4){0.f, 0.f, 0.f, 0.f};

  // prologue: tiles 0 and 1 fully staged; vmcnt(8) -> tile 0 resident
  // (B(1)^4 + A(1)^4 = 8 newest may still fly).
  stageB(0, 0); stageB(0, 1); stageA(0, 0); stageA(0, 1);
  stageB(1, 0); stageB(1, 1); stageA(1, 0); stageA(1, 1);
  asm volatile("s_waitcnt vmcnt(8)" ::: "memory");
  __builtin_amdgcn_s_barrier();
  __builtin_amdgcn_sched_barrier(0);

  bf16x8 a[4][2], b[4][2];
#pragma unroll 1
  for (int k2 = 0; k2 < 8; ++k2) {
#pragma unroll
    for (int par = 0; par < 2; ++par) {
      const int kt = k2 * 2 + par;
      const u16* pA = sAf + par * 16384;
      const u16* pB = sBf + par * 16384;
      const bool st = (k2 < 7);                  // kt < 14: stage kt+2

      // -------- phase 0: (qm0, qn0) --------
#pragma unroll
      for (int m4 = 0; m4 < 4; ++m4) {
        a[m4][0] = *(const bf16x8*)(pA + (vA0 + m4 * 1024));
        a[m4][1] = *(const bf16x8*)(pA + ((vA0 ^ 32) + m4 * 1024));
      }
#pragma unroll
      for (int n2 = 0; n2 < 2; ++n2) {
        b[n2][0] = *(const bf16x8*)(pB + (vB0 + n2 * 1024));
        b[n2][1] = *(const bf16x8*)(pB + ((vB0 ^ 32) + n2 * 1024));
      }
      __builtin_amdgcn_s_barrier();
      asm volatile("s_waitcnt lgkmcnt(0)" ::: "memory");
      __builtin_amdgcn_sched_barrier(0);
      __builtin_amdgcn_s_setprio(1);
#pragma unroll
      for (int m4 = 0; m4 < 4; ++m4)
#pragma unroll
        for (int n2 = 0; n2 < 2; ++n2)
#pragma unroll
          for (int kk = 0; kk < 2; ++kk)
            acc[m4][n2] = __builtin_amdgcn_mfma_f32_16x16x32_bf16(
                a[m4][kk], b[n2][kk], acc[m4][n2], 0, 0, 0);
      __builtin_amdgcn_s_setprio(0);
      __builtin_amdgcn_s_barrier();
      __builtin_amdgcn_sched_barrier(0);

      // -------- phase 1: (qm0, qn1) --------
#pragma unroll
      for (int n2 = 0; n2 < 2; ++n2) {
        b[2 + n2][0] = *(const bf16x8*)(pB + (vB0 + (2 + n2) * 1024));
        b[2 + n2][1] = *(const bf16x8*)(pB + ((vB0 ^ 32) + (2 + n2) * 1024));
      }
      __builtin_amdgcn_s_barrier();
      asm volatile("s_waitcnt lgkmcnt(0)" ::: "memory");
      __builtin_amdgcn_sched_barrier(0);
      __builtin_amdgcn_s_setprio(1);
#pragma unroll
      for (int m4 = 0; m4 < 4; ++m4)
#pragma unroll
        for (int n2 = 0; n2 < 2; ++n2)
#pragma unroll
          for (int kk = 0; kk < 2; ++kk)
            acc[m4][2 + n2] = __builtin_amdgcn_mfma_f32_16x16x32_bf16(
                a[m4][kk], b[2 + n2][kk], acc[m4][2 + n2], 0, 0, 0);
      __builtin_amdgcn_s_setprio(0);
      __builtin_amdgcn_s_barrier();
      __builtin_amdgcn_sched_barrier(0);

      // -------- phase 2: (qm1, qn0) + stage B(kt+2) both halves --------
#pragma unroll
      for (int m4 = 0; m4 < 4; ++m4) {
        a[m4][0] = *(const bf16x8*)(pA + (vA0 + (4 + m4) * 1024));
        a[m4][1] = *(const bf16x8*)(pA + ((vA0 ^ 32) + (4 + m4) * 1024));
      }
      if (st) { stageB(kt + 2, 0); stageB(kt + 2, 1); }
      __builtin_amdgcn_s_barrier();
      asm volatile("s_waitcnt lgkmcnt(0)" ::: "memory");
      __builtin_amdgcn_sched_barrier(0);
      __builtin_amdgcn_s_setprio(1);
#pragma unroll
      for (int m4 = 0; m4 < 4; ++m4)
#pragma unroll
        for (int n2 = 0; n2 < 2; ++n2)
#pragma unroll
          for (int kk = 0; kk < 2; ++kk)
            acc[4 + m4][n2] = __builtin_amdgcn_mfma_f32_16x16x32_bf16(
                a[m4][kk], b[n2][kk], acc[4 + m4][n2], 0, 0, 0);
      __builtin_amdgcn_s_setprio(0);
      __builtin_amdgcn_s_barrier();
      __builtin_amdgcn_sched_barrier(0);

      // -------- phase 3: (qm1, qn1) + stage A(kt+2) both halves --------
      if (st) { stageA(kt + 2, 0); stageA(kt + 2, 1); }
      if (st) { asm volatile("s_waitcnt vmcnt(8)" ::: "memory"); }
      else if (par == 0) { asm volatile("s_waitcnt vmcnt(0)" ::: "memory"); }
      // kt==15: nothing outstanding, no wait.
      __builtin_amdgcn_s_barrier();
      asm volatile("s_waitcnt lgkmcnt(0)" ::: "memory");
      __builtin_amdgcn_sched_barrier(0);
      __builtin_amdgcn_s_setprio(1);
#pragma unroll
      for (int m4 = 0; m4 < 4; ++m4)
#pragma unroll
        for (int n2 = 0; n2 < 2; ++n2)
#pragma unroll
          for (int kk = 0; kk < 2; ++kk)
            acc[4 + m4][2 + n2] = __builtin_amdgcn_mfma_f32_16x16x32_bf16(
                a[m4][kk], b[2 + n2][kk], acc[4 + m4][2 + n2], 0, 0, 0);
      __builtin_amdgcn_s_setprio(0);
      __builtin_amdgcn_s_barrier();
      __builtin_amdgcn_sched_barrier(0);
    }
  }

  // epilogue: h2 = acc + beff, stored BF16 at row pitch 2048 u16 (= 4096 B).
  // C/D: col=lane&15, row=quad*4+r.
  const float* bb = beff + task * D_HID;
  const size_t mBase = (size_t)by * 256 + wm * 128;
  const int nb0 = bx * 256 + wn * 64;
#pragma unroll
  for (int mf = 0; mf < 8; ++mf)
#pragma unroll
    for (int nf = 0; nf < 4; ++nf) {
      const int n = nb0 + nf * 16 + l15;
      const float bval = bb[n];
#pragma unroll
      for (int r = 0; r < 4; ++r) {
        const size_t m = mBase + mf * 16 + quad * 4 + r;
        outb[m * 2048 + n] = f2bf(acc[mf][nf][r] + bval);
      }
    }
}

// ---- ln4: out = LN(bf16(h2) + resid). h2 bf16 lives in the first 2048 B of
//      each 4096 B out-row slot; wave loads its OWN row to regs, then
//      overwrites the slot with the fp32 result (read-before-write, no race).
__global__ __launch_bounds__(256) void ln4(float* __restrict__ out,
                                           const float* __restrict__ resid,
                                           const float* __restrict__ gamma,
                                           const float* __restrict__ beta) {
  const int row = blockIdx.x * 4 + (threadIdx.x >> 6);
  const int lane = threadIdx.x & 63;
  const u16* hb = (const u16*)out + (size_t)row * 2048;
  const float* rp = resid + (size_t)row * D_HID;
  float* po = out + (size_t)row * D_HID;
  float4 v[4];
#pragma unroll
  for (int k = 0; k < 4; ++k) {
    const int c = lane * 4 + k * 256;
    const u16x4v h = *(const u16x4v*)(hb + c);
    const float4 r = *(const float4*)(rp + c);
    v[k].x = bf2f(h[0]) + r.x; v[k].y = bf2f(h[1]) + r.y;
    v[k].z = bf2f(h[2]) + r.z; v[k].w = bf2f(h[3]) + r.w;
  }
  float s = 0.f, q = 0.f;
#pragma unroll
  for (int k = 0; k < 4; ++k) {
    s += v[k].x + v[k].y + v[k].z + v[k].w;
    q += v[k].x * v[k].x + v[k].y * v[k].y + v[k].z * v[k].z + v[k].w * v[k].w;
  }
#pragma unroll
  for (int m = 1; m < 64; m <<= 1) { s += __shfl_xor(s, m); q += __shfl_xor(q, m); }
  const float mu  = s * (1.f / (float)D_HID);
  const float var = q * (1.f / (float)D_HID) - mu * mu;
  const float inv = rsqrtf(var + LN_EPS);
#pragma unroll
  for (int k = 0; k < 4; ++k) {
    const int c = lane * 4 + k * 256;
    const float4 g  = *(const float4*)(gamma + c);
    const float4 bb = *(const float4*)(beta + c);
    float4 o;
    o.x = (v[k].x - mu) * inv * g.x + bb.x;
    o.y = (v[k].y - mu) * inv * g.y + bb.y;
    o.z = (v[k].z - mu) * inv * g.z + bb.z;
    o.w = (v[k].w - mu) * inv * g.w + bb.w;
    *(float4*)(po + c) = o;
  }
}

extern "C" void kernel_launch(void* const* d_in, const int* in_sizes, int n_in,
                              void* d_out, int out_size, void* d_ws, size_t ws_size,
                              hipStream_t stream) {
  const float* hs    = (const float*)d_in[0];  // [16,2048,1024] fp32
  const float* inp   = (const float*)d_in[1];  // [16,2048,1024] fp32
  const float* W     = (const float*)d_in[2];  // [1024,1024] fp32
  const float* b     = (const float*)d_in[3];  // [1024]
  const float* lA    = (const float*)d_in[4];  // [5,4,1024]
  const float* lB    = (const float*)d_in[5];  // [5,1024,4]
  const float* gamma = (const float*)d_in[6];
  const float* beta  = (const float*)d_in[7];
  const int*   mask  = (const int*)d_in[8];    // [16]
  float* out = (float*)d_out;

  // Workspace (81.9 MiB):
  //  [0,64M)      hs_bf bf16
  //  [64M,+4M)    Wc fp32
  //  [+4M,+10M)   Weff bf16 [5][1024][1024]; first 8.5 MB double as
  //               Whi/Wlo/WhiT/WloT + lApad hi/lo (dead before K3 writes).
  //  tail         A2 (80K), beff (20K)
  char* wsb = (char*)d_ws;
  u16*   hs_bf = (u16*)wsb;
  float* Wc    = (float*)(wsb + 67108864);
  u16*   weff  = (u16*)(wsb + 71303168);
  u16*   Whi   = weff;
  u16*   Wlo   = weff + 1048576;
  u16*   WhiT  = weff + 2097152;
  u16*   WloT  = weff + 3145728;
  u16*   lAh   = weff + 4194304;
  u16*   lAl   = weff + 4325376;
  float* A2    = (float*)(wsb + 81788928);
  float* beff  = (float*)(wsb + 81871360);

  k1_prep<<<1032 + CVT_K1_BLKS, 256, 0, stream>>>(
      hs, hs_bf, W, Whi, Wlo, WhiT, WloT, lA, lAh, lAl);
  k2_s2<<<272 + CVT_K2_BLKS, 256, 0, stream>>>(
      Whi, Wlo, WhiT, WloT, lAh, lAl, hs, hs_bf, Wc, A2);
  k3_weff<<<5120 + CVT_K3_BLKS, 256, 0, stream>>>(
      Wc, A2, lB, lA, W, b, hs, hs_bf, weff, beff);
  gemm_main<<<512, 512, 0, stream>>>(hs_bf, weff, beff, mask, (u16*)out);
  ln4<<<M_TOT / 4, 256, 0, stream>>>(out, inp, gamma, beta);
}

// Round 15
// 455.249 us; speedup vs baseline: 1.0630x; 1.0144x over previous
//
#include <hip/hip_runtime.h>
#include <hip/hip_bf16.h>
#include <stdint.h>

// JinaEmbeddingsV3SelfOutput, algebraically folded:
//   h2 = hs @ Weff_t^T + beff_t,   Weff_t = W@W + 0.25*B_t@(A_t@W)  [per task]
//   beff_t = W@b + b + 0.25*B_t@(A_t@b)
//   out = LN(h2 + input)
// R15 = R14 + gemm_main barrier thinning (8 -> 3 barriers per K-tile).
//   Hazard audit: only three barriers are load-bearing --
//     bar-A (ph1 exit): all B-reads(kt) done before stageB(kt+2) overwrites
//       the same parity buffer (each wave's lgkmcnt(0) precedes arrival);
//     bar-B (ph2 exit): all A-reads(kt) done before stageA(kt+2);
//     bar-C (ph3 end, after vmcnt): tile kt+1 residency globalized before
//       ph0(kt+1) reads (waves read each other's staged segments).
//   The five removed barriers separated reads-from-reads / reg-only MFMA.
//   vmcnt(8) now sits AFTER MFMA q11 (no dep) so the HBM drain overlaps the
//   matrix pipe. Per-wave lgkm(0)+sched_barrier(0) before each dependent
//   MFMA retained (rule #18). No arithmetic change.
#define D_HID 1024
#define M_TOT 32768
#define LN_EPS 1e-5f

typedef __bf16 bf16x8 __attribute__((ext_vector_type(8)));
typedef float f32x4 __attribute__((ext_vector_type(4)));
typedef unsigned short u16;
typedef u16 u16x8 __attribute__((ext_vector_type(8)));
typedef u16 u16x4v __attribute__((ext_vector_type(4)));

__device__ __forceinline__ float bf2f(u16 x) {
  union { unsigned int u; float f; } c; c.u = ((unsigned int)x) << 16; return c.f;
}
__device__ __forceinline__ u16 f2bf(float f) {
  union { __bf16 h; u16 u; } c; c.h = (__bf16)f; return c.u;  // RNE
}
// Async global->LDS, 16B/lane. LDS dest is wave-uniform base + lane*16.
__device__ __forceinline__ void gld16(const u16* g, u16* lds_wave_base) {
  __builtin_amdgcn_global_load_lds(
      (__attribute__((address_space(1))) unsigned int*)g,
      (__attribute__((address_space(3))) unsigned int*)lds_wave_base, 16, 0, 0);
}

// one-shot cvt job: thread converts 8 fp32 -> 8 bf16 (proven-best shape).
__device__ __forceinline__ void cvt_job(const float* __restrict__ hs,
                                        u16* __restrict__ hs_bf, size_t idx) {
  const float4 a = *(const float4*)(hs + idx * 8);
  const float4 b = *(const float4*)(hs + idx * 8 + 4);
  u16x8 o;
  o[0] = f2bf(a.x); o[1] = f2bf(a.y); o[2] = f2bf(a.z); o[3] = f2bf(a.w);
  o[4] = f2bf(b.x); o[5] = f2bf(b.y); o[6] = f2bf(b.z); o[7] = f2bf(b.w);
  *(u16x8*)(hs_bf + idx * 8) = o;
}

// cvt slice bounds (thread-jobs of 8 elems; total 32768*1024/8 = 4194304)
#define CVT_K1_BLKS 5440
#define CVT_K2_BLKS 5472
#define CVT_K3_BLKS 5472
#define CVT_K2_OFF  (CVT_K1_BLKS * 256)                    // 1392640
#define CVT_K3_OFF  ((CVT_K1_BLKS + CVT_K2_BLKS) * 256)    // 2793472

// ---- K1: W split+transpose (0..1023), lA zero-pad split (1024..1031),
//          cvt slice (1032..6471) ----
__global__ __launch_bounds__(256) void k1_prep(
    const float* __restrict__ hs, u16* __restrict__ hs_bf,
    const float* __restrict__ W, u16* __restrict__ hi, u16* __restrict__ lo,
    u16* __restrict__ hiT, u16* __restrict__ loT,
    const float* __restrict__ lA, u16* __restrict__ lAh, u16* __restrict__ lAl) {
  __shared__ float tile[32][33];
  const int bid = blockIdx.x, tid = threadIdx.x;
  if (bid >= 1032) {
    cvt_job(hs, hs_bf, (size_t)(bid - 1032) * 256 + tid);
    return;
  }
  if (bid >= 1024) {                  // lA pad+split: 128x1024, rows >=20 zero
    const int b = bid - 1024;
    for (int i = tid; i < 16 * 1024; i += 256) {
      const int r = b * 16 + (i >> 10), c = i & 1023;
      const float v = (r < 20) ? lA[(size_t)r * 1024 + c] : 0.f;
      const u16 h = f2bf(v);
      lAh[(size_t)r * 1024 + c] = h;
      lAl[(size_t)r * 1024 + c] = f2bf(v - bf2f(h));
    }
    return;
  }
  const int bj = bid & 31, bi = bid >> 5;
  const int tx = tid & 31, ty = tid >> 5;
#pragma unroll
  for (int r0 = 0; r0 < 32; r0 += 8) {
    const int r = r0 + ty;
    const size_t o = (size_t)(bi * 32 + r) * D_HID + bj * 32 + tx;
    const float v = W[o];
    tile[r][tx] = v;
    const u16 h = f2bf(v);
    hi[o] = h; lo[o] = f2bf(v - bf2f(h));
  }
  __syncthreads();
#pragma unroll
  for (int r0 = 0; r0 < 32; r0 += 8) {
    const int r = r0 + ty;
    const float v = tile[tx][r];
    const size_t o = (size_t)(bj * 32 + r) * D_HID + bi * 32 + tx;
    const u16 h = f2bf(v);
    hiT[o] = h; loT[o] = f2bf(v - bf2f(h));
  }
}

// ---- K2: [W; lApad] @ W split-bf16 MFMA 64x64 (0..271) + cvt slice (272..5743) ----
__global__ __launch_bounds__(256) void k2_s2(
    const u16* __restrict__ Ah, const u16* __restrict__ Al,
    const u16* __restrict__ Bh, const u16* __restrict__ Bl,
    const u16* __restrict__ lAh, const u16* __restrict__ lAl,
    const float* __restrict__ hs, u16* __restrict__ hs_bf,
    float* __restrict__ C, float* __restrict__ A2) {
  __shared__ __align__(16) u16 smem[4][64 * 32];   // Ah,Al,Bh,Bl tiles
  const int bid = blockIdx.x, tid = threadIdx.x;
  if (bid >= 272) {
    cvt_job(hs, hs_bf, (size_t)CVT_K2_OFF + (size_t)(bid - 272) * 256 + tid);
    return;
  }
  const int wave = tid >> 6, lane = tid & 63;
  const int by = bid >> 4, bx = bid & 15;
  const bool isA2 = (by == 16);
  const u16* Asel_h = isA2 ? lAh : Ah;
  const u16* Asel_l = isA2 ? lAl : Al;
  const int arow0 = isA2 ? 0 : by * 64;
  const u16* gsel = (wave == 0) ? Asel_h : (wave == 1) ? Asel_l
                  : (wave == 2) ? Bh : Bl;
  const int rb = (wave < 2) ? arow0 : bx * 64;
  const u16* gp = gsel + (size_t)(rb + (lane >> 2)) * D_HID + (lane & 3) * 8;
  u16* sb = &smem[wave][0];

  const int l15 = lane & 15, quad = lane >> 4;
  const int wm = wave >> 1, wn = wave & 1;
  const int fA = (wm * 32 + l15) * 32 + quad * 8;
  const int fB = (wn * 32 + l15) * 32 + quad * 8;
  f32x4 acc[2][2];
#pragma unroll
  for (int m = 0; m < 2; ++m)
#pragma unroll
    for (int n = 0; n < 2; ++n) acc[m][n] = (f32x4){0.f, 0.f, 0.f, 0.f};

  for (int k0 = 0; k0 < D_HID; k0 += 32) {
    __syncthreads();
#pragma unroll
    for (int q = 0; q < 4; ++q)
      gld16(gp + (size_t)q * 16 * D_HID, sb + q * 512);
    gp += 32;
    __syncthreads();
    bf16x8 ahf[2], alf[2], bhf[2], blf[2];
#pragma unroll
    for (int m = 0; m < 2; ++m) {
      ahf[m] = *(const bf16x8*)(&smem[0][fA + m * 512]);
      alf[m] = *(const bf16x8*)(&smem[1][fA + m * 512]);
    }
#pragma unroll
    for (int n = 0; n < 2; ++n) {
      bhf[n] = *(const bf16x8*)(&smem[2][fB + n * 512]);
      blf[n] = *(const bf16x8*)(&smem[3][fB + n * 512]);
    }
#pragma unroll
    for (int m = 0; m < 2; ++m)
#pragma unroll
      for (int n = 0; n < 2; ++n) {
        acc[m][n] = __builtin_amdgcn_mfma_f32_16x16x32_bf16(ahf[m], bhf[n], acc[m][n], 0, 0, 0);
        acc[m][n] = __builtin_amdgcn_mfma_f32_16x16x32_bf16(alf[m], bhf[n], acc[m][n], 0, 0, 0);
        acc[m][n] = __builtin_amdgcn_mfma_f32_16x16x32_bf16(ahf[m], blf[n], acc[m][n], 0, 0, 0);
      }
  }
  const int nn0 = bx * 64 + wn * 32;
#pragma unroll
  for (int m = 0; m < 2; ++m)
#pragma unroll
    for (int n = 0; n < 2; ++n) {
      const int nn = nn0 + n * 16 + l15;
#pragma unroll
      for (int r = 0; r < 4; ++r) {
        const int lr = wm * 32 + m * 16 + quad * 4 + r;
        if (!isA2) {
          C[(size_t)(by * 64 + lr) * D_HID + nn] = acc[m][n][r];
        } else if (lr < 20) {
          A2[(size_t)lr * D_HID + nn] = acc[m][n][r];
        }
      }
    }
}

// ---- K3: weff+beff (0..5119, n=bid&1023 t=bid>>10) + cvt (5120..10591) ----
__global__ __launch_bounds__(256) void k3_weff(
    const float* __restrict__ Wc, const float* __restrict__ A2,
    const float* __restrict__ lB, const float* __restrict__ lA,
    const float* __restrict__ W, const float* __restrict__ bvec,
    const float* __restrict__ hs, u16* __restrict__ hs_bf,
    u16* __restrict__ Weff, float* __restrict__ beff) {
  const int bid = blockIdx.x, tid = threadIdx.x;
  if (bid >= 5120) {
    cvt_job(hs, hs_bf, (size_t)CVT_K3_OFF + (size_t)(bid - 5120) * 256 + tid);
    return;
  }
  const int n = bid & 1023, t = bid >> 10;
  const int wave = tid >> 6, lane = tid & 63;
  float br[4];
#pragma unroll
  for (int r = 0; r < 4; ++r) br[r] = lB[(size_t)t * 4096 + n * 4 + r];
  float4 v = *(const float4*)(Wc + (size_t)n * D_HID + tid * 4);
#pragma unroll
  for (int r = 0; r < 4; ++r) {
    const float4 a2 = *(const float4*)(A2 + (size_t)(t * 4 + r) * D_HID + tid * 4);
    const float s = 0.25f * br[r];
    v.x += s * a2.x; v.y += s * a2.y; v.z += s * a2.z; v.w += s * a2.w;
  }
  u16x4v o; o[0] = f2bf(v.x); o[1] = f2bf(v.y); o[2] = f2bf(v.z); o[3] = f2bf(v.w);
  *(u16x4v*)(Weff + (size_t)t * 1048576 + (size_t)n * D_HID + tid * 4) = o;
  const float4 bb = *(const float4*)(bvec + tid * 4);
  float p[5];
  {
    const float4 wr = *(const float4*)(W + (size_t)n * D_HID + tid * 4);
    p[0] = wr.x * bb.x + wr.y * bb.y + wr.z * bb.z + wr.w * bb.w;
  }
#pragma unroll
  for (int r = 0; r < 4; ++r) {
    const float4 ar = *(const float4*)(lA + (size_t)(t * 4 + r) * D_HID + tid * 4);
    p[1 + r] = ar.x * bb.x + ar.y * bb.y + ar.z * bb.z + ar.w * bb.w;
  }
#pragma unroll
  for (int m = 1; m < 64; m <<= 1)
#pragma unroll
    for (int jj = 0; jj < 5; ++jj) p[jj] += __shfl_xor(p[jj], m);
  __shared__ float red[4][5];
  if (lane == 0)
#pragma unroll
    for (int jj = 0; jj < 5; ++jj) red[wave][jj] = p[jj];
  __syncthreads();
  if (tid == 0) {
    float P = 0.f, Cr[4] = {0.f, 0.f, 0.f, 0.f};
#pragma unroll
    for (int w = 0; w < 4; ++w) {
      P += red[w][0];
#pragma unroll
      for (int r = 0; r < 4; ++r) Cr[r] += red[w][1 + r];
    }
    const float e = br[0]*Cr[0] + br[1]*Cr[1] + br[2]*Cr[2] + br[3]*Cr[3];
    beff[t * D_HID + n] = P + bvec[n] + 0.25f * e;
  }
}

// ---- main GEMM: h2 = hs_bf @ Weff[task]^T + beff, stored BF16 (R13).
// 256x256, BK=64, 8 waves, 128 KB dbuf, XOR octet swizzle, R14 leads
// (A=4 phases, B=5). R15: 3 barriers/K-tile --
//   ph0: ds a(0..63), b(nf0-1); lgkm; MFMA q00.
//   ph1: ds b(nf2-3); lgkm; MFMA q01; BAR-A (B-buf consumed).
//   ph2: ds a(64..127); stage B(kt+2) x2; lgkm; MFMA q10; BAR-B (A consumed).
//   ph3: stage A(kt+2) x2; MFMA q11 (regs only); vmcnt(8); BAR-C (kt+1
//        resident globally -> ph0(kt+1) reads safe).
// Per-wave lgkm(0)+sched_barrier before each LDS-dependent MFMA (rule #18).
// Tail: kt==14 vmcnt(0); kt==15 no stages, no wait.
__global__ __launch_bounds__(512, 1) void gemm_main(
    const u16* __restrict__ Ag, const u16* __restrict__ Wf,
    const float* __restrict__ beff, const int* __restrict__ mask,
    u16* __restrict__ outb) {
  __shared__ __align__(16) u16 sAf[2 * 16384];
  __shared__ __align__(16) u16 sBf[2 * 16384];
  const int tid = threadIdx.x, wave = tid >> 6, lane = tid & 63;
  const int L = blockIdx.x;                 // 512 blocks
  const int xcd = L & 7, j = L >> 3;
  const int bx = j & 3;                     // N-tile 0..3
  const int by = xcd * 16 + (j >> 2);       // M-tile 0..127; XCD-clustered
  const int task = mask[by >> 3];           // 256-row tile never crosses batch
  const u16* Bg = Wf + (size_t)task * (D_HID * D_HID);

  const int acol = ((lane & 7) ^ (lane >> 3)) * 8;
  const int aBase = (by * 256 + wave * 8 + (lane >> 3)) * D_HID + acol;
  const int bBase = (bx * 256 + wave * 8 + (lane >> 3)) * D_HID + acol;

  auto stageA = [&](int ktar, int half) {
#pragma unroll
    for (int q = 0; q < 2; ++q)
      gld16(Ag + (aBase + ktar * 64 + half * 131072 + q * 65536),
            sAf + ((ktar & 1) * 16384 + half * 8192 + q * 4096 + wave * 512));
  };
  auto stageB = [&](int ktar, int half) {
#pragma unroll
    for (int q = 0; q < 2; ++q)
      gld16(Bg + (bBase + ktar * 64 + half * 131072 + q * 65536),
            sBf + ((ktar & 1) * 16384 + half * 8192 + q * 4096 + wave * 512));
  };

  const int wm = wave >> 2, wn = wave & 3;
  const int l15 = lane & 15, quad = lane >> 4, l7 = lane & 7;
  const int vA0 = (wm * 128 + l15) * 64 + ((quad ^ l7) * 8);
  const int vB0 = (wn * 64 + l15) * 64 + ((quad ^ l7) * 8);

  f32x4 acc[8][4];
#pragma unroll
  for (int i = 0; i < 8; ++i)
#pragma unroll
    for (int jn = 0; jn < 4; ++jn) acc[i][jn] = (f32x4){0.f, 0.f, 0.f, 0.f};

  // prologue: tiles 0 and 1 fully staged; vmcnt(8) -> tile 0 resident.
  stageB(0, 0); stageB(0, 1); stageA(0, 0); stageA(0, 1);
  stageB(1, 0); stageB(1, 1); stageA(1, 0); stageA(1, 1);
  asm volatile("s_waitcnt vmcnt(8)" ::: "memory");
  __builtin_amdgcn_s_barrier();
  __builtin_amdgcn_sched_barrier(0);

  bf16x8 a[4][2], b[4][2];
#pragma unroll 1
  for (int k2 = 0; k2 < 8; ++k2) {
#pragma unroll
    for (int par = 0; par < 2; ++par) {
      const int kt = k2 * 2 + par;
      const u16* pA = sAf + par * 16384;
      const u16* pB = sBf + par * 16384;
      const bool st = (k2 < 7);                  // kt < 14: stage kt+2

      // -------- phase 0: (qm0, qn0) --------
#pragma unroll
      for (int m4 = 0; m4 < 4; ++m4) {
        a[m4][0] = *(const bf16x8*)(pA + (vA0 + m4 * 1024));
        a[m4][1] = *(const bf16x8*)(pA + ((vA0 ^ 32) + m4 * 1024));
      }
#pragma unroll
      for (int n2 = 0; n2 < 2; ++n2) {
        b[n2][0] = *(const bf16x8*)(pB + (vB0 + n2 * 1024));
        b[n2][1] = *(const bf16x8*)(pB + ((vB0 ^ 32) + n2 * 1024));
      }
      asm volatile("s_waitcnt lgkmcnt(0)" ::: "memory");
      __builtin_amdgcn_sched_barrier(0);
      __builtin_amdgcn_s_setprio(1);
#pragma unroll
      for (int m4 = 0; m4 < 4; ++m4)
#pragma unroll
        for (int n2 = 0; n2 < 2; ++n2)
#pragma unroll
          for (int kk = 0; kk < 2; ++kk)
            acc[m4][n2] = __builtin_amdgcn_mfma_f32_16x16x32_bf16(
                a[m4][kk], b[n2][kk], acc[m4][n2], 0, 0, 0);
      __builtin_amdgcn_s_setprio(0);

      // -------- phase 1: (qm0, qn1) --------
#pragma unroll
      for (int n2 = 0; n2 < 2; ++n2) {
        b[2 + n2][0] = *(const bf16x8*)(pB + (vB0 + (2 + n2) * 1024));
        b[2 + n2][1] = *(const bf16x8*)(pB + ((vB0 ^ 32) + (2 + n2) * 1024));
      }
      asm volatile("s_waitcnt lgkmcnt(0)" ::: "memory");
      __builtin_amdgcn_sched_barrier(0);
      __builtin_amdgcn_s_setprio(1);
#pragma unroll
      for (int m4 = 0; m4 < 4; ++m4)
#pragma unroll
        for (int n2 = 0; n2 < 2; ++n2)
#pragma unroll
          for (int kk = 0; kk < 2; ++kk)
            acc[m4][2 + n2] = __builtin_amdgcn_mfma_f32_16x16x32_bf16(
                a[m4][kk], b[2 + n2][kk], acc[m4][2 + n2], 0, 0, 0);
      __builtin_amdgcn_s_setprio(0);
      __builtin_amdgcn_s_barrier();          // BAR-A: B-buf kt consumed
      __builtin_amdgcn_sched_barrier(0);

      // -------- phase 2: (qm1, qn0) + stage B(kt+2) both halves --------
#pragma unroll
      for (int m4 = 0; m4 < 4; ++m4) {
        a[m4][0] = *(const bf16x8*)(pA + (vA0 + (4 + m4) * 1024));
        a[m4][1] = *(const bf16x8*)(pA + ((vA0 ^ 32) + (4 + m4) * 1024));
      }
      if (st) { stageB(kt + 2, 0); stageB(kt + 2, 1); }
      asm volatile("s_waitcnt lgkmcnt(0)" ::: "memory");
      __builtin_amdgcn_sched_barrier(0);
      __builtin_amdgcn_s_setprio(1);
#pragma unroll
      for (int m4 = 0; m4 < 4; ++m4)
#pragma unroll
        for (int n2 = 0; n2 < 2; ++n2)
#pragma unroll
          for (int kk = 0; kk < 2; ++kk)
            acc[4 + m4][n2] = __builtin_amdgcn_mfma_f32_16x16x32_bf16(
                a[m4][kk], b[n2][kk], acc[4 + m4][n2], 0, 0, 0);
      __builtin_amdgcn_s_setprio(0);
      __builtin_amdgcn_s_barrier();          // BAR-B: A-buf kt consumed
      __builtin_amdgcn_sched_barrier(0);

      // -------- phase 3: (qm1, qn1) + stage A(kt+2); drain overlaps MFMA ----
      if (st) { stageA(kt + 2, 0); stageA(kt + 2, 1); }
      __builtin_amdgcn_s_setprio(1);
#pragma unroll
      for (int m4 = 0; m4 < 4; ++m4)
#pragma unroll
        for (int n2 = 0; n2 < 2; ++n2)
#pragma unroll
          for (int kk = 0; kk < 2; ++kk)
            acc[4 + m4][2 + n2] = __builtin_amdgcn_mfma_f32_16x16x32_bf16(
                a[m4][kk], b[2 + n2][kk], acc[4 + m4][2 + n2], 0, 0, 0);
      __builtin_amdgcn_s_setprio(0);
      if (st)            { asm volatile("s_waitcnt vmcnt(8)" ::: "memory"); }
      else if (par == 0) { asm volatile("s_waitcnt vmcnt(0)" ::: "memory"); }
      __builtin_amdgcn_s_barrier();          // BAR-C: tile kt+1 resident
      __builtin_amdgcn_sched_barrier(0);
    }
  }

  // epilogue: h2 = acc + beff, stored BF16 at row pitch 2048 u16 (= 4096 B).
  // C/D: col=lane&15, row=quad*4+r.
  const float* bb = beff + task * D_HID;
  const size_t mBase = (size_t)by * 256 + wm * 128;
  const int nb0 = bx * 256 + wn * 64;
#pragma unroll
  for (int mf = 0; mf < 8; ++mf)
#pragma unroll
    for (int nf = 0; nf < 4; ++nf) {
      const int n = nb0 + nf * 16 + l15;
      const float bval = bb[n];
#pragma unroll
      for (int r = 0; r < 4; ++r) {
        const size_t m = mBase + mf * 16 + quad * 4 + r;
        outb[m * 2048 + n] = f2bf(acc[mf][nf][r] + bval);
      }
    }
}

// ---- ln4: out = LN(bf16(h2) + resid). h2 bf16 lives in the first 2048 B of
//      each 4096 B out-row slot; wave loads its OWN row to regs, then
//      overwrites the slot with the fp32 result (read-before-write, no race).
__global__ __launch_bounds__(256) void ln4(float* __restrict__ out,
                                           const float* __restrict__ resid,
                                           const float* __restrict__ gamma,
                                           const float* __restrict__ beta) {
  const int row = blockIdx.x * 4 + (threadIdx.x >> 6);
  const int lane = threadIdx.x & 63;
  const u16* hb = (const u16*)out + (size_t)row * 2048;
  const float* rp = resid + (size_t)row * D_HID;
  float* po = out + (size_t)row * D_HID;
  float4 v[4];
#pragma unroll
  for (int k = 0; k < 4; ++k) {
    const int c = lane * 4 + k * 256;
    const u16x4v h = *(const u16x4v*)(hb + c);
    const float4 r = *(const float4*)(rp + c);
    v[k].x = bf2f(h[0]) + r.x; v[k].y = bf2f(h[1]) + r.y;
    v[k].z = bf2f(h[2]) + r.z; v[k].w = bf2f(h[3]) + r.w;
  }
  float s = 0.f, q = 0.f;
#pragma unroll
  for (int k = 0; k < 4; ++k) {
    s += v[k].x + v[k].y + v[k].z + v[k].w;
    q += v[k].x * v[k].x + v[k].y * v[k].y + v[k].z * v[k].z + v[k].w * v[k].w;
  }
#pragma unroll
  for (int m = 1; m < 64; m <<= 1) { s += __shfl_xor(s, m); q += __shfl_xor(q, m); }
  const float mu  = s * (1.f / (float)D_HID);
  const float var = q * (1.f / (float)D_HID) - mu * mu;
  const float inv = rsqrtf(var + LN_EPS);
#pragma unroll
  for (int k = 0; k < 4; ++k) {
    const int c = lane * 4 + k * 256;
    const float4 g  = *(const float4*)(gamma + c);
    const float4 bb = *(const float4*)(beta + c);
    float4 o;
    o.x = (v[k].x - mu) * inv * g.x + bb.x;
    o.y = (v[k].y - mu) * inv * g.y + bb.y;
    o.z = (v[k].z - mu) * inv * g.z + bb.z;
    o.w = (v[k].w - mu) * inv * g.w + bb.w;
    *(float4*)(po + c) = o;
  }
}

extern "C" void kernel_launch(void* const* d_in, const int* in_sizes, int n_in,
                              void* d_out, int out_size, void* d_ws, size_t ws_size,
                              hipStream_t stream) {
  const float* hs    = (const float*)d_in[0];  // [16,2048,1024] fp32
  const float* inp   = (const float*)d_in[1];  // [16,2048,1024] fp32
  const float* W     = (const float*)d_in[2];  // [1024,1024] fp32
  const float* b     = (const float*)d_in[3];  // [1024]
  const float* lA    = (const float*)d_in[4];  // [5,4,1024]
  const float* lB    = (const float*)d_in[5];  // [5,1024,4]
  const float* gamma = (const float*)d_in[6];
  const float* beta  = (const float*)d_in[7];
  const int*   mask  = (const int*)d_in[8];    // [16]
  float* out = (float*)d_out;

  // Workspace (81.9 MiB):
  //  [0,64M)      hs_bf bf16
  //  [64M,+4M)    Wc fp32
  //  [+4M,+10M)   Weff bf16 [5][1024][1024]; first 8.5 MB double as
  //               Whi/Wlo/WhiT/WloT + lApad hi/lo (dead before K3 writes).
  //  tail         A2 (80K), beff (20K)
  char* wsb = (char*)d_ws;
  u16*   hs_bf = (u16*)wsb;
  float* Wc    = (float*)(wsb + 67108864);
  u16*   weff  = (u16*)(wsb + 71303168);
  u16*   Whi   = weff;
  u16*   Wlo   = weff + 1048576;
  u16*   WhiT  = weff + 2097152;
  u16*   WloT  = weff + 3145728;
  u16*   lAh   = weff + 4194304;
  u16*   lAl   = weff + 4325376;
  float* A2    = (float*)(wsb + 81788928);
  float* beff  = (float*)(wsb + 81871360);

  k1_prep<<<1032 + CVT_K1_BLKS, 256, 0, stream>>>(
      hs, hs_bf, W, Whi, Wlo, WhiT, WloT, lA, lAh, lAl);
  k2_s2<<<272 + CVT_K2_BLKS, 256, 0, stream>>>(
      Whi, Wlo, WhiT, WloT, lAh, lAl, hs, hs_bf, Wc, A2);
  k3_weff<<<5120 + CVT_K3_BLKS, 256, 0, stream>>>(
      Wc, A2, lB, lA, W, b, hs, hs_bf, weff, beff);
  gemm_main<<<512, 512, 0, stream>>>(hs_bf, weff, beff, mask, (u16*)out);
  ln4<<<M_TOT / 4, 256, 0, stream>>>(out, inp, gamma, beta);
}